// Round 9
// baseline (153.821 us; speedup 1.0000x reference)
//
#include <hip/hip_runtime.h>
#include <hip/hip_bf16.h>

// 2D DCT-II (4096x4096 fp32).  Round 8:
//   K1  = R4's dct_rows2 (row DCT, LDS FFT4096, 2 rows packed, 41 us)
//   K2a = column-pass step 1: per (b, col-pair): z[a]=Y[sigma(64a+b)][col],
//         reg FFT64 (compile-time twiddles), mid-twiddle W4096^{bq} -> ws
//   K2b = column-pass step 2: conj-split BEFORE FFT, reg FFT64, expk, store.
// R7 bug: 256-thread launch bounds made the allocator cap at 80 VGPR ->
// float2 t[64] spilled to scratch (83 us).  Fix: K2a/K2b are ONE WAVE per
// block, __launch_bounds__(64) (R6 precedent: 192 VGPR, no spill).
// Plan: K1(x->out) ; K2a(out->ws) ; K2b(ws->out).  d_ws needs 64 MB.

#define L 4096

__device__ __forceinline__ int SWZ(int e) {
    return e ^ (((e >> 4) ^ (e >> 8)) & 15);
}

__device__ __forceinline__ int digitrev12(int n) {
    int r = 0;
#pragma unroll
    for (int i = 0; i < 6; ++i) { r = (r << 2) | (n & 3); n >>= 2; }
    return r;
}

__device__ __forceinline__ float2 cmul(float2 a, float2 b) {
    return make_float2(a.x * b.x - a.y * b.y, a.x * b.y + a.y * b.x);
}

__device__ __forceinline__ void bfly4(float2& x0, float2& x1, float2& x2, float2& x3) {
    float t0x = x0.x + x2.x, t0y = x0.y + x2.y;
    float t1x = x0.x - x2.x, t1y = x0.y - x2.y;
    float t2x = x1.x + x3.x, t2y = x1.y + x3.y;
    float t3x = x1.x - x3.x, t3y = x1.y - x3.y;
    x0 = make_float2(t0x + t2x, t0y + t2y);
    x1 = make_float2(t1x + t3y, t1y - t3x);   // t1 + (-i)*t3
    x2 = make_float2(t0x - t2x, t0y - t2y);
    x3 = make_float2(t1x - t3y, t1y + t3x);   // t1 + (+i)*t3
}

// e^{-2*pi*i*m/64}; with compile-time m, folds to float literals.
__device__ __forceinline__ float2 W64C(int m) {
    constexpr float C[17] = {1.f, 0.995184726672197f, 0.980785280403230f,
        0.956940335732209f, 0.923879532511287f, 0.881921264348355f,
        0.831469612302545f, 0.773010453362737f, 0.707106781186548f,
        0.634393284163645f, 0.555570233019602f, 0.471396736825998f,
        0.382683432365090f, 0.290284677254462f, 0.195090322016128f,
        0.098017140329561f, 0.f};
    m &= 63;
    float c, s;
    if (m <= 16)      { c =  C[m];      s =  C[16 - m]; }
    else if (m <= 32) { c = -C[32 - m]; s =  C[m - 16]; }
    else if (m <= 48) { c = -C[m - 32]; s = -C[48 - m]; }
    else              { c =  C[64 - m]; s = -C[m - 48]; }
    return make_float2(c, -s);
}

// In-place radix-4 DIT FFT64 on registers.  Input: reg i = v[drev6(i)]
// (caller folds the digit reversal into its loads).  Output: natural order.
__device__ __forceinline__ void fft64r(float2* t) {
#pragma unroll
    for (int g = 0; g < 16; ++g)
        bfly4(t[4*g], t[4*g+1], t[4*g+2], t[4*g+3]);
#pragma unroll
    for (int j = 0; j < 4; ++j) {
#pragma unroll
        for (int g = 0; g < 4; ++g) {
            int base = 16*g + j;
            if (j) {
                t[base+4]  = cmul(t[base+4],  W64C(4*j));
                t[base+8]  = cmul(t[base+8],  W64C(8*j));
                t[base+12] = cmul(t[base+12], W64C(12*j));
            }
            bfly4(t[base], t[base+4], t[base+8], t[base+12]);
        }
    }
#pragma unroll
    for (int j = 0; j < 16; ++j) {
        if (j) {
            t[j+16] = cmul(t[j+16], W64C(j));
            t[j+32] = cmul(t[j+32], W64C(2*j));
            t[j+48] = cmul(t[j+48], W64C(3*j));
        }
        bfly4(t[j], t[j+16], t[j+32], t[j+48]);
    }
}

// ---------------- K1: row DCT (R4 structure, unchanged) ----------------

template <int Q>
__device__ __forceinline__ void stage_pair(float2* lds, int t) {
    const int j = t & (Q - 1);
    const int G = t / Q;
    const int base = G * 16 * Q + j;

    float2 v[4][4];
#pragma unroll
    for (int b = 0; b < 4; ++b)
#pragma unroll
        for (int a = 0; a < 4; ++a)
            v[a][b] = lds[SWZ(base + (a + 4 * b) * Q)];

    if (Q > 1) {
        float c1, s1;
        __sincosf((float)j * (-6.2831853071795864769f / (4.0f * (float)Q)), &s1, &c1);
        float2 w1 = make_float2(c1, s1);
        float2 w2 = cmul(w1, w1);
        float2 w3 = cmul(w2, w1);
#pragma unroll
        for (int b = 0; b < 4; ++b) {
            v[1][b] = cmul(v[1][b], w1);
            v[2][b] = cmul(v[2][b], w2);
            v[3][b] = cmul(v[3][b], w3);
        }
    }
#pragma unroll
    for (int b = 0; b < 4; ++b) bfly4(v[0][b], v[1][b], v[2][b], v[3][b]);

    float2 u;
    if (Q == 1) {
        u = make_float2(1.0f, 0.0f);
    } else {
        float cu, su;
        __sincosf((float)j * (-6.2831853071795864769f / (16.0f * (float)Q)), &su, &cu);
        u = make_float2(cu, su);
    }
    const float2 E = make_float2(0.92387953251128674f, -0.38268343236508977f);
    float2 w = u;
#pragma unroll
    for (int a = 0; a < 4; ++a) {
        if (!(Q == 1 && a == 0)) {
            float2 W2 = cmul(w, w);
            float2 W3 = cmul(W2, w);
            v[a][1] = cmul(v[a][1], w);
            v[a][2] = cmul(v[a][2], W2);
            v[a][3] = cmul(v[a][3], W3);
        }
        bfly4(v[a][0], v[a][1], v[a][2], v[a][3]);
        if (a < 3) w = cmul(w, E);
    }

#pragma unroll
    for (int b = 0; b < 4; ++b)
#pragma unroll
        for (int a = 0; a < 4; ++a)
            lds[SWZ(base + (a + 4 * b) * Q)] = v[a][b];
}

__global__ __launch_bounds__(256)
void dct_rows2_kernel(const float* __restrict__ in, float* __restrict__ out) {
    __shared__ float2 lds[L];   // 32 KB

    const int r0 = blockIdx.x * 2;
    const int t = threadIdx.x;
    const float* rowA = in + (size_t)r0 * L;
    const float* rowB = rowA + L;

#pragma unroll
    for (int w = 0; w < 8; ++w) {
        int n = w * 256 + t;
        float2 fa = *reinterpret_cast<const float2*>(&rowA[2 * n]);
        float2 fb = *reinterpret_cast<const float2*>(&rowB[2 * n]);
        int p = digitrev12(n);
        lds[SWZ(p)]        = make_float2(fa.x, fb.x);
        lds[SWZ(4095 - p)] = make_float2(fa.y, fb.y);
    }
    __syncthreads();

    stage_pair<1>(lds, t);
    __syncthreads();
    stage_pair<16>(lds, t);
    __syncthreads();
    stage_pair<256>(lds, t);
    __syncthreads();

    float* outA = out + (size_t)r0 * L;
    float* outB = outA + L;
#pragma unroll
    for (int w = 0; w < 16; ++w) {
        int k = w * 256 + t;
        float2 Zk = lds[SWZ(k)];
        int m = (L - k) & (L - 1);
        float2 Zm = lds[SWZ(m)];

        float vax = 0.5f * (Zk.x + Zm.x);
        float vay = 0.5f * (Zk.y - Zm.y);
        float vbx = 0.5f * (Zk.y + Zm.y);
        float vby = 0.5f * (Zm.x - Zk.x);

        float th = (float)k * 3.8349519697141029e-4f;   // pi/8192
        float sk, ck;
        __sincosf(th, &sk, &ck);
        outA[k] = vax * ck + vay * sk;
        outB[k] = vbx * ck + vby * sk;
    }
}

// ---------------- K2a: column pass, step 1 (one wave per block) ----------------
__global__ __launch_bounds__(64)
void fft64_col_a(const float* __restrict__ Y, float* __restrict__ ws) {
    const int c = threadIdx.x;              // lane = column
    const int b = blockIdx.x;               // 0..63
    const int T = blockIdx.y;               // 0..31
    const int ca = T * 128 + c;
    const int cb = ca + 64;

    float2 z[64];
#pragma unroll
    for (int i = 0; i < 64; ++i) {
        const int a = ((i & 3) << 4) | (i & 12) | (i >> 4);   // drev6(i)
        int j = 64 * a + b;
        int row = (a < 32) ? (2 * j) : (8191 - 2 * j);        // Makhoul sigma
        const float* rp = Y + (size_t)row * L;
        z[i] = make_float2(rp[ca], rp[cb]);
    }

    fft64r(z);

    // mid twiddle: z[q] *= e^{-2 pi i b q / 4096}, wave-uniform chain
    const float ang = (float)b * -1.5339807878856412e-3f;     // -2pi b/4096
    float2 m1; __sincosf(ang, &m1.y, &m1.x);
#pragma unroll
    for (int q0 = 0; q0 < 64; q0 += 8) {
        float2 wv;
        if (q0 == 0) wv = make_float2(1.0f, 0.0f);
        else         __sincosf(ang * (float)q0, &wv.y, &wv.x);
#pragma unroll
        for (int d = 0; d < 8; ++d) {
            int q = q0 + d;
            if (q) z[q] = cmul(z[q], wv);
            if (d < 7) wv = cmul(wv, m1);
        }
    }

    float2* wp = reinterpret_cast<float2*>(ws) + (size_t)b * 2048 + (size_t)T * 64 + c;
#pragma unroll
    for (int q = 0; q < 64; ++q)
        wp[(size_t)q * 131072] = z[q];
}

// ---------------- K2b: column pass, step 2 (one wave per block) ----------------
//   Aseq[b] = 0.5*(H[q][b] + conj(H[q'][b])*fac_b),  q'=(64-q)&63,
//   Bseq[b] = -0.5i*(H[q][b] - conj(H[q'][b])*fac_b),
//   fac_b = W64^b for q>=1, 1 for q==0.   F/G[64p+q] = FFT64_b{seq}[p].
__global__ __launch_bounds__(64)
void fft64_col_b(const float* __restrict__ wsf, float* __restrict__ out) {
    const int c  = threadIdx.x;             // lane = column
    const int qa = blockIdx.x;              // 0..31
    const int T  = blockIdx.y;              // 0..31
    const int w  = blockIdx.z;              // 0..3
    const int q  = (w < 2) ? qa : ((qa == 0) ? 32 : 64 - qa);
    const int isB = w & 1;
    const int qp = (q == 0) ? 0 : ((64 - q) & 63);
    const bool selfp = (qp == q);

    const float2* wsc = reinterpret_cast<const float2*>(wsf);
    const float2* hq = wsc + (size_t)q  * 131072 + (size_t)T * 64 + c;
    const float2* hp = wsc + (size_t)qp * 131072 + (size_t)T * 64 + c;

    float2 t[64];
#pragma unroll
    for (int i = 0; i < 64; ++i) {
        const int bb = ((i & 3) << 4) | (i & 12) | (i >> 4);  // drev6(i)
        float2 a0 = hq[(size_t)bb * 2048];
        float2 p0 = selfp ? a0 : hp[(size_t)bb * 2048];
        float2 pc = make_float2(p0.x, -p0.y);
        float2 m  = (q == 0) ? pc : cmul(pc, W64C(bb));
        if (!isB) {
            t[i] = make_float2(0.5f * (a0.x + m.x), 0.5f * (a0.y + m.y));
        } else {
            float vx = a0.x - m.x, vy = a0.y - m.y;
            t[i] = make_float2(0.5f * vy, -0.5f * vx);        // -i/2 * v
        }
    }

    fft64r(t);

    const int col = T * 128 + (isB ? 64 : 0) + c;
    float* op = out + col;
    const float2 M = make_float2(0.99969881869620425f, 0.024541228522912288f); // e^{+i pi/128}
    float2 e;
#pragma unroll
    for (int p = 0; p < 64; ++p) {
        if ((p & 15) == 0)
            __sincosf((float)(64 * p + q) * 3.8349519697141029e-4f, &e.y, &e.x);
        op[(size_t)(64 * p + q) * L] = t[p].x * e.x + t[p].y * e.y;
        e = cmul(e, M);
    }
}

extern "C" void kernel_launch(void* const* d_in, const int* in_sizes, int n_in,
                              void* d_out, int out_size, void* d_ws, size_t ws_size,
                              hipStream_t stream) {
    const float* x = (const float*)d_in[0];
    float* out = (float*)d_out;
    float* ws  = (float*)d_ws;   // needs 64 MB

    dct_rows2_kernel<<<L / 2, 256, 0, stream>>>(x, out);           // rows: x -> Y(out)
    fft64_col_a<<<dim3(64, 32), 64, 0, stream>>>(out, ws);         // Y -> H(ws)
    fft64_col_b<<<dim3(32, 32, 4), 64, 0, stream>>>(ws, out);      // H -> final(out)
}

// Round 10
// 146.057 us; speedup vs baseline: 1.0532x; 1.0532x over previous
//
#include <hip/hip_runtime.h>
#include <hip/hip_bf16.h>
#include <utility>

// 2D DCT-II (4096x4096 fp32).  Round 9:
//   K1  = R4's dct_rows2 (row DCT, LDS FFT4096, 2 rows packed, 41 us)
//   K2a = column-pass step 1 (reg FFT64, mid-twiddle) -> ws
//   K2b = column-pass step 2 (conj-split before FFT, reg FFT64, expk) -> out
// R7/R8 bug was NOT launch bounds: VGPR=80 at both 256 and 64 threads means
// the float2[64] array was never SROA-promoted (rule #20: non-constant
// indices -> scratch).  Fix: static_for (fold expression) everywhere the
// array is touched -> every index is a compile-time constant by construction;
// twiddles via template<int> -> literals.  Geometry back to R8 (4 waves/block
// share H slices in L1), __launch_bounds__(256,2) (cap 256 VGPR).
// Plan: K1(x->out) ; K2a(out->ws) ; K2b(ws->out).  d_ws needs 64 MB.

#define L 4096

// ---- compile-time for: f(integral_constant<int,0>) ... f(ic<N-1>) ----
template <class F, int... Is>
__device__ __forceinline__ void sf_impl(F f, std::integer_sequence<int, Is...>) {
    (f(std::integral_constant<int, Is>{}), ...);
}
template <int N, class F>
__device__ __forceinline__ void static_for(F f) {
    sf_impl(f, std::make_integer_sequence<int, N>{});
}

__device__ __forceinline__ int SWZ(int e) {
    return e ^ (((e >> 4) ^ (e >> 8)) & 15);
}

__device__ __forceinline__ int digitrev12(int n) {
    int r = 0;
#pragma unroll
    for (int i = 0; i < 6; ++i) { r = (r << 2) | (n & 3); n >>= 2; }
    return r;
}

__device__ __forceinline__ float2 cmul(float2 a, float2 b) {
    return make_float2(a.x * b.x - a.y * b.y, a.x * b.y + a.y * b.x);
}

__device__ __forceinline__ void bfly4(float2& x0, float2& x1, float2& x2, float2& x3) {
    float t0x = x0.x + x2.x, t0y = x0.y + x2.y;
    float t1x = x0.x - x2.x, t1y = x0.y - x2.y;
    float t2x = x1.x + x3.x, t2y = x1.y + x3.y;
    float t3x = x1.x - x3.x, t3y = x1.y - x3.y;
    x0 = make_float2(t0x + t2x, t0y + t2y);
    x1 = make_float2(t1x + t3y, t1y - t3x);   // t1 + (-i)*t3
    x2 = make_float2(t0x - t2x, t0y - t2y);
    x3 = make_float2(t1x - t3y, t1y + t3x);   // t1 + (+i)*t3
}

// e^{-2*pi*i*M/64} as compile-time literals.
template <int M>
__device__ __forceinline__ float2 W64T() {
    constexpr float C[17] = {1.f, 0.995184726672197f, 0.980785280403230f,
        0.956940335732209f, 0.923879532511287f, 0.881921264348355f,
        0.831469612302545f, 0.773010453362737f, 0.707106781186548f,
        0.634393284163645f, 0.555570233019602f, 0.471396736825998f,
        0.382683432365090f, 0.290284677254462f, 0.195090322016128f,
        0.098017140329561f, 0.f};
    constexpr int m = M & 63;
    constexpr float c = (m <= 16) ?  C[m]
                      : (m <= 32) ? -C[32 - m]
                      : (m <= 48) ? -C[m - 32]
                      :              C[64 - m];
    constexpr float s = (m <= 16) ?  C[16 - m]
                      : (m <= 32) ?  C[m - 16]
                      : (m <= 48) ? -C[48 - m]
                      :             -C[m - 48];
    return make_float2(c, -s);
}

// In-place radix-4 DIT FFT64, reg i = v[drev6(i)] on input, natural output.
// All indices compile-time constants (static_for), twiddles literal.
__device__ __forceinline__ void fft64r(float2* t) {
    static_for<16>([&](auto G) {
        constexpr int g = decltype(G)::value;
        bfly4(t[4*g], t[4*g+1], t[4*g+2], t[4*g+3]);
    });
    static_for<4>([&](auto J) {
        constexpr int j = decltype(J)::value;
        static_for<4>([&](auto G) {
            constexpr int g = decltype(G)::value;
            constexpr int base = 16*g + j;
            if constexpr (j != 0) {
                t[base+4]  = cmul(t[base+4],  W64T<4*j>());
                t[base+8]  = cmul(t[base+8],  W64T<8*j>());
                t[base+12] = cmul(t[base+12], W64T<12*j>());
            }
            bfly4(t[base], t[base+4], t[base+8], t[base+12]);
        });
    });
    static_for<16>([&](auto J) {
        constexpr int j = decltype(J)::value;
        if constexpr (j != 0) {
            t[j+16] = cmul(t[j+16], W64T<j>());
            t[j+32] = cmul(t[j+32], W64T<2*j>());
            t[j+48] = cmul(t[j+48], W64T<3*j>());
        }
        bfly4(t[j], t[j+16], t[j+32], t[j+48]);
    });
}

// ---------------- K1: row DCT (R4 structure, unchanged) ----------------

template <int Q>
__device__ __forceinline__ void stage_pair(float2* lds, int t) {
    const int j = t & (Q - 1);
    const int G = t / Q;
    const int base = G * 16 * Q + j;

    float2 v[4][4];
#pragma unroll
    for (int b = 0; b < 4; ++b)
#pragma unroll
        for (int a = 0; a < 4; ++a)
            v[a][b] = lds[SWZ(base + (a + 4 * b) * Q)];

    if (Q > 1) {
        float c1, s1;
        __sincosf((float)j * (-6.2831853071795864769f / (4.0f * (float)Q)), &s1, &c1);
        float2 w1 = make_float2(c1, s1);
        float2 w2 = cmul(w1, w1);
        float2 w3 = cmul(w2, w1);
#pragma unroll
        for (int b = 0; b < 4; ++b) {
            v[1][b] = cmul(v[1][b], w1);
            v[2][b] = cmul(v[2][b], w2);
            v[3][b] = cmul(v[3][b], w3);
        }
    }
#pragma unroll
    for (int b = 0; b < 4; ++b) bfly4(v[0][b], v[1][b], v[2][b], v[3][b]);

    float2 u;
    if (Q == 1) {
        u = make_float2(1.0f, 0.0f);
    } else {
        float cu, su;
        __sincosf((float)j * (-6.2831853071795864769f / (16.0f * (float)Q)), &su, &cu);
        u = make_float2(cu, su);
    }
    const float2 E = make_float2(0.92387953251128674f, -0.38268343236508977f);
    float2 w = u;
#pragma unroll
    for (int a = 0; a < 4; ++a) {
        if (!(Q == 1 && a == 0)) {
            float2 W2 = cmul(w, w);
            float2 W3 = cmul(W2, w);
            v[a][1] = cmul(v[a][1], w);
            v[a][2] = cmul(v[a][2], W2);
            v[a][3] = cmul(v[a][3], W3);
        }
        bfly4(v[a][0], v[a][1], v[a][2], v[a][3]);
        if (a < 3) w = cmul(w, E);
    }

#pragma unroll
    for (int b = 0; b < 4; ++b)
#pragma unroll
        for (int a = 0; a < 4; ++a)
            lds[SWZ(base + (a + 4 * b) * Q)] = v[a][b];
}

__global__ __launch_bounds__(256)
void dct_rows2_kernel(const float* __restrict__ in, float* __restrict__ out) {
    __shared__ float2 lds[L];   // 32 KB

    const int r0 = blockIdx.x * 2;
    const int t = threadIdx.x;
    const float* rowA = in + (size_t)r0 * L;
    const float* rowB = rowA + L;

#pragma unroll
    for (int w = 0; w < 8; ++w) {
        int n = w * 256 + t;
        float2 fa = *reinterpret_cast<const float2*>(&rowA[2 * n]);
        float2 fb = *reinterpret_cast<const float2*>(&rowB[2 * n]);
        int p = digitrev12(n);
        lds[SWZ(p)]        = make_float2(fa.x, fb.x);
        lds[SWZ(4095 - p)] = make_float2(fa.y, fb.y);
    }
    __syncthreads();

    stage_pair<1>(lds, t);
    __syncthreads();
    stage_pair<16>(lds, t);
    __syncthreads();
    stage_pair<256>(lds, t);
    __syncthreads();

    float* outA = out + (size_t)r0 * L;
    float* outB = outA + L;
#pragma unroll
    for (int w = 0; w < 16; ++w) {
        int k = w * 256 + t;
        float2 Zk = lds[SWZ(k)];
        int m = (L - k) & (L - 1);
        float2 Zm = lds[SWZ(m)];

        float vax = 0.5f * (Zk.x + Zm.x);
        float vay = 0.5f * (Zk.y - Zm.y);
        float vbx = 0.5f * (Zk.y + Zm.y);
        float vby = 0.5f * (Zm.x - Zk.x);

        float th = (float)k * 3.8349519697141029e-4f;   // pi/8192
        float sk, ck;
        __sincosf(th, &sk, &ck);
        outA[k] = vax * ck + vay * sk;
        outB[k] = vbx * ck + vby * sk;
    }
}

// ---------------- K2a: column pass, step 1 ----------------
// Per wave: fixed b.  z[i] = v[64*drev(i)+b][col], coalesced 512B reads.
// After FFT64: z[q] *= W4096^{bq}; store H[q][b][T][c] to ws.
__global__ __launch_bounds__(256, 2)
void fft64_col_a(const float* __restrict__ Y, float* __restrict__ ws) {
    const int c = threadIdx.x & 63;
    const int w = threadIdx.x >> 6;
    const int b = blockIdx.x * 4 + w;       // 0..63
    const int T = blockIdx.y;               // 0..31
    const int ca = T * 128 + c;
    const int cb = ca + 64;

    float2 z[64];
    static_for<64>([&](auto I) {
        constexpr int i = decltype(I)::value;
        constexpr int a = ((i & 3) << 4) | (i & 12) | (i >> 4);   // drev6(i)
        int row;
        if constexpr (a < 32) row = 128 * a + 2 * b;              // sigma(64a+b)
        else                  row = 8191 - 128 * a - 2 * b;
        const float* rp = Y + (size_t)row * L;
        z[i] = make_float2(rp[ca], rp[cb]);
    });

    fft64r(z);

    // mid twiddle: z[q] *= e^{-2 pi i b q / 4096}, wave-uniform chain
    const float ang = (float)b * -1.5339807878856412e-3f;     // -2pi b/4096
    float2 m1; __sincosf(ang, &m1.y, &m1.x);
    static_for<8>([&](auto Q0) {
        constexpr int q0 = 8 * decltype(Q0)::value;
        float2 wv;
        if constexpr (q0 == 0) wv = make_float2(1.0f, 0.0f);
        else                   __sincosf(ang * (float)q0, &wv.y, &wv.x);
        static_for<8>([&](auto D) {
            constexpr int d = decltype(D)::value;
            constexpr int q = q0 + d;
            if constexpr (q != 0) z[q] = cmul(z[q], wv);
            if constexpr (d < 7) wv = cmul(wv, m1);
        });
    });

    float2* wp = reinterpret_cast<float2*>(ws) + (size_t)b * 2048 + (size_t)T * 64 + c;
    static_for<64>([&](auto Q) {
        constexpr int q = decltype(Q)::value;
        wp[(size_t)q * 131072] = z[q];
    });
}

// ---------------- K2b: column pass, step 2 ----------------
//   Aseq[b] = 0.5*(H[q][b] + conj(H[q'][b])*fac_b),  q'=(64-q)&63,
//   Bseq[b] = -0.5i*(H[q][b] - conj(H[q'][b])*fac_b),
//   fac_b = W64^b for q>=1, 1 for q==0.   F/G[64p+q] = FFT64_b{seq}[p].
// 4 waves/block = (A/B) x (q, 64-q) -> share H slices in L1.
__global__ __launch_bounds__(256, 2)
void fft64_col_b(const float* __restrict__ wsf, float* __restrict__ out) {
    const int c  = threadIdx.x & 63;
    const int w  = threadIdx.x >> 6;
    const int qa = blockIdx.x;              // 0..31
    const int T  = blockIdx.y;              // 0..31
    const int q  = (w < 2) ? qa : ((qa == 0) ? 32 : 64 - qa);
    const int isB = w & 1;
    const int qp = (q == 0) ? 0 : ((64 - q) & 63);
    const bool selfp = (qp == q);

    const float2* wsc = reinterpret_cast<const float2*>(wsf);
    const float2* hq = wsc + (size_t)q  * 131072 + (size_t)T * 64 + c;
    const float2* hp = wsc + (size_t)qp * 131072 + (size_t)T * 64 + c;

    float2 t[64];
    static_for<64>([&](auto I) {
        constexpr int i = decltype(I)::value;
        constexpr int bb = ((i & 3) << 4) | (i & 12) | (i >> 4);  // drev6(i)
        float2 a0 = hq[(size_t)bb * 2048];
        float2 p0 = selfp ? a0 : hp[(size_t)bb * 2048];
        float2 pc = make_float2(p0.x, -p0.y);
        float2 m;
        if (q == 0) m = pc;
        else        m = cmul(pc, W64T<bb>());
        if (!isB) {
            t[i] = make_float2(0.5f * (a0.x + m.x), 0.5f * (a0.y + m.y));
        } else {
            float vx = a0.x - m.x, vy = a0.y - m.y;
            t[i] = make_float2(0.5f * vy, -0.5f * vx);        // -i/2 * v
        }
    });

    fft64r(t);

    const int col = T * 128 + (isB ? 64 : 0) + c;
    float* op = out + col;
    const float2 M = make_float2(0.99969881869620425f, 0.024541228522912288f); // e^{+i pi/128}
    float2 e;
    static_for<64>([&](auto P) {
        constexpr int p = decltype(P)::value;
        if constexpr ((p & 15) == 0)
            __sincosf((float)(64 * p) * 3.8349519697141029e-4f + (float)q * 3.8349519697141029e-4f, &e.y, &e.x);
        op[(size_t)(64 * p) * L + (size_t)q * L] = t[p].x * e.x + t[p].y * e.y;
        e = cmul(e, M);
    });
}

extern "C" void kernel_launch(void* const* d_in, const int* in_sizes, int n_in,
                              void* d_out, int out_size, void* d_ws, size_t ws_size,
                              hipStream_t stream) {
    const float* x = (const float*)d_in[0];
    float* out = (float*)d_out;
    float* ws  = (float*)d_ws;   // needs 64 MB

    dct_rows2_kernel<<<L / 2, 256, 0, stream>>>(x, out);        // rows: x -> Y(out)
    fft64_col_a<<<dim3(16, 32), 256, 0, stream>>>(out, ws);     // Y -> H(ws)
    fft64_col_b<<<dim3(32, 32), 256, 0, stream>>>(ws, out);     // H -> final(out)
}

// Round 11
// 118.372 us; speedup vs baseline: 1.2995x; 1.2339x over previous
//
#include <hip/hip_runtime.h>
#include <hip/hip_bf16.h>

// 2D DCT-II (4096x4096 fp32).  Round 10:
//   K1  = R4's dct_rows2 (row DCT, LDS FFT4096, 2 rows packed, 41 us)
//   K2a = column-pass step 1 (reg FFT64, mid-twiddle) -> ws
//   K2b = column-pass step 2 (conj-split before FFT, reg FFT64, expk) -> out
// R7-R9: float2[64] per-thread array NEVER got SROA-promoted (VGPR stuck at
// 80 across three code shapes) -> every butterfly round-tripped scratch.
// This round: NO array at all.  64 NAMED float2 registers via X-macros;
// all 48 butterflies + twiddles expanded with literal indices/constants.
// Registers by construction - there is no alloca.
// Plan: K1(x->out) ; K2a(out->ws) ; K2b(ws->out).  d_ws needs 64 MB.

#define L 4096

__device__ __host__ constexpr int drev6c(int i) {
    return ((i & 3) << 4) | (i & 12) | ((i >> 4) & 3);
}

__device__ __forceinline__ int SWZ(int e) {
    return e ^ (((e >> 4) ^ (e >> 8)) & 15);
}

__device__ __forceinline__ int digitrev12(int n) {
    int r = 0;
#pragma unroll
    for (int i = 0; i < 6; ++i) { r = (r << 2) | (n & 3); n >>= 2; }
    return r;
}

__device__ __forceinline__ float2 cmul(float2 a, float2 b) {
    return make_float2(a.x * b.x - a.y * b.y, a.x * b.y + a.y * b.x);
}

__device__ __forceinline__ void bfly4(float2& x0, float2& x1, float2& x2, float2& x3) {
    float t0x = x0.x + x2.x, t0y = x0.y + x2.y;
    float t1x = x0.x - x2.x, t1y = x0.y - x2.y;
    float t2x = x1.x + x3.x, t2y = x1.y + x3.y;
    float t3x = x1.x - x3.x, t3y = x1.y - x3.y;
    x0 = make_float2(t0x + t2x, t0y + t2y);
    x1 = make_float2(t1x + t3y, t1y - t3x);   // t1 + (-i)*t3
    x2 = make_float2(t0x - t2x, t0y - t2y);
    x3 = make_float2(t1x - t3y, t1y + t3x);   // t1 + (+i)*t3
}

// e^{-2*pi*i*M/64} as compile-time literals.
template <int M>
__device__ __forceinline__ float2 W64T() {
    constexpr float C[17] = {1.f, 0.995184726672197f, 0.980785280403230f,
        0.956940335732209f, 0.923879532511287f, 0.881921264348355f,
        0.831469612302545f, 0.773010453362737f, 0.707106781186548f,
        0.634393284163645f, 0.555570233019602f, 0.471396736825998f,
        0.382683432365090f, 0.290284677254462f, 0.195090322016128f,
        0.098017140329561f, 0.f};
    constexpr int m = M & 63;
    constexpr float c = (m <= 16) ?  C[m]
                      : (m <= 32) ? -C[32 - m]
                      : (m <= 48) ? -C[m - 32]
                      :              C[64 - m];
    constexpr float s = (m <= 16) ?  C[16 - m]
                      : (m <= 32) ?  C[m - 16]
                      : (m <= 48) ? -C[48 - m]
                      :             -C[m - 48];
    return make_float2(c, -s);
}

// ---- X-macro plumbing: 64 named float2 registers ----
#define FOR64(X) X(0) X(1) X(2) X(3) X(4) X(5) X(6) X(7) X(8) X(9) X(10) X(11) \
  X(12) X(13) X(14) X(15) X(16) X(17) X(18) X(19) X(20) X(21) X(22) X(23) \
  X(24) X(25) X(26) X(27) X(28) X(29) X(30) X(31) X(32) X(33) X(34) X(35) \
  X(36) X(37) X(38) X(39) X(40) X(41) X(42) X(43) X(44) X(45) X(46) X(47) \
  X(48) X(49) X(50) X(51) X(52) X(53) X(54) X(55) X(56) X(57) X(58) X(59) \
  X(60) X(61) X(62) X(63)

#define DECLZ(i) float2 z##i;

#define B4(i0,i1,i2,i3) bfly4(z##i0, z##i1, z##i2, z##i3);
#define TB4(i0,i1,i2,i3,w) { \
    z##i1 = cmul(z##i1, W64T<(w)>());     \
    z##i2 = cmul(z##i2, W64T<2*(w)>());   \
    z##i3 = cmul(z##i3, W64T<3*(w)>());   \
    bfly4(z##i0, z##i1, z##i2, z##i3); }

// In-register FFT64 on named regs z0..z63.  Input: z_i = v[drev6(i)]
// (callers fold the digit reversal into their loads).  Output: z_q = V[q].
#define FFT64_BODY() \
  /* stage 0 (radix-4, Q=1) */ \
  B4(0,1,2,3)     B4(4,5,6,7)     B4(8,9,10,11)   B4(12,13,14,15) \
  B4(16,17,18,19) B4(20,21,22,23) B4(24,25,26,27) B4(28,29,30,31) \
  B4(32,33,34,35) B4(36,37,38,39) B4(40,41,42,43) B4(44,45,46,47) \
  B4(48,49,50,51) B4(52,53,54,55) B4(56,57,58,59) B4(60,61,62,63) \
  /* stage 1 (Q=4): base=16g+j, twiddle W64^{4j} */ \
  B4(0,4,8,12)        B4(16,20,24,28)      B4(32,36,40,44)      B4(48,52,56,60) \
  TB4(1,5,9,13,4)     TB4(17,21,25,29,4)   TB4(33,37,41,45,4)   TB4(49,53,57,61,4) \
  TB4(2,6,10,14,8)    TB4(18,22,26,30,8)   TB4(34,38,42,46,8)   TB4(50,54,58,62,8) \
  TB4(3,7,11,15,12)   TB4(19,23,27,31,12)  TB4(35,39,43,47,12)  TB4(51,55,59,63,12) \
  /* stage 2 (Q=16): j, j+16, j+32, j+48, twiddle W64^{j} */ \
  B4(0,16,32,48) \
  TB4(1,17,33,49,1)   TB4(2,18,34,50,2)    TB4(3,19,35,51,3)    TB4(4,20,36,52,4) \
  TB4(5,21,37,53,5)   TB4(6,22,38,54,6)    TB4(7,23,39,55,7)    TB4(8,24,40,56,8) \
  TB4(9,25,41,57,9)   TB4(10,26,42,58,10)  TB4(11,27,43,59,11)  TB4(12,28,44,60,12) \
  TB4(13,29,45,61,13) TB4(14,30,46,62,14)  TB4(15,31,47,63,15)

// ---------------- K1: row DCT (R4 structure, unchanged) ----------------

template <int Q>
__device__ __forceinline__ void stage_pair(float2* lds, int t) {
    const int j = t & (Q - 1);
    const int G = t / Q;
    const int base = G * 16 * Q + j;

    float2 v[4][4];
#pragma unroll
    for (int b = 0; b < 4; ++b)
#pragma unroll
        for (int a = 0; a < 4; ++a)
            v[a][b] = lds[SWZ(base + (a + 4 * b) * Q)];

    if (Q > 1) {
        float c1, s1;
        __sincosf((float)j * (-6.2831853071795864769f / (4.0f * (float)Q)), &s1, &c1);
        float2 w1 = make_float2(c1, s1);
        float2 w2 = cmul(w1, w1);
        float2 w3 = cmul(w2, w1);
#pragma unroll
        for (int b = 0; b < 4; ++b) {
            v[1][b] = cmul(v[1][b], w1);
            v[2][b] = cmul(v[2][b], w2);
            v[3][b] = cmul(v[3][b], w3);
        }
    }
#pragma unroll
    for (int b = 0; b < 4; ++b) bfly4(v[0][b], v[1][b], v[2][b], v[3][b]);

    float2 u;
    if (Q == 1) {
        u = make_float2(1.0f, 0.0f);
    } else {
        float cu, su;
        __sincosf((float)j * (-6.2831853071795864769f / (16.0f * (float)Q)), &su, &cu);
        u = make_float2(cu, su);
    }
    const float2 E = make_float2(0.92387953251128674f, -0.38268343236508977f);
    float2 w = u;
#pragma unroll
    for (int a = 0; a < 4; ++a) {
        if (!(Q == 1 && a == 0)) {
            float2 W2 = cmul(w, w);
            float2 W3 = cmul(W2, w);
            v[a][1] = cmul(v[a][1], w);
            v[a][2] = cmul(v[a][2], W2);
            v[a][3] = cmul(v[a][3], W3);
        }
        bfly4(v[a][0], v[a][1], v[a][2], v[a][3]);
        if (a < 3) w = cmul(w, E);
    }

#pragma unroll
    for (int b = 0; b < 4; ++b)
#pragma unroll
        for (int a = 0; a < 4; ++a)
            lds[SWZ(base + (a + 4 * b) * Q)] = v[a][b];
}

__global__ __launch_bounds__(256)
void dct_rows2_kernel(const float* __restrict__ in, float* __restrict__ out) {
    __shared__ float2 lds[L];   // 32 KB

    const int r0 = blockIdx.x * 2;
    const int t = threadIdx.x;
    const float* rowA = in + (size_t)r0 * L;
    const float* rowB = rowA + L;

#pragma unroll
    for (int w = 0; w < 8; ++w) {
        int n = w * 256 + t;
        float2 fa = *reinterpret_cast<const float2*>(&rowA[2 * n]);
        float2 fb = *reinterpret_cast<const float2*>(&rowB[2 * n]);
        int p = digitrev12(n);
        lds[SWZ(p)]        = make_float2(fa.x, fb.x);
        lds[SWZ(4095 - p)] = make_float2(fa.y, fb.y);
    }
    __syncthreads();

    stage_pair<1>(lds, t);
    __syncthreads();
    stage_pair<16>(lds, t);
    __syncthreads();
    stage_pair<256>(lds, t);
    __syncthreads();

    float* outA = out + (size_t)r0 * L;
    float* outB = outA + L;
#pragma unroll
    for (int w = 0; w < 16; ++w) {
        int k = w * 256 + t;
        float2 Zk = lds[SWZ(k)];
        int m = (L - k) & (L - 1);
        float2 Zm = lds[SWZ(m)];

        float vax = 0.5f * (Zk.x + Zm.x);
        float vay = 0.5f * (Zk.y - Zm.y);
        float vbx = 0.5f * (Zk.y + Zm.y);
        float vby = 0.5f * (Zm.x - Zk.x);

        float th = (float)k * 3.8349519697141029e-4f;   // pi/8192
        float sk, ck;
        __sincosf(th, &sk, &ck);
        outA[k] = vax * ck + vay * sk;
        outB[k] = vbx * ck + vby * sk;
    }
}

// ---------------- K2a: column pass, step 1 ----------------
// Per wave: fixed b.  z_i = v[64*drev6(i)+b][col] (coalesced 512B reads).
// After FFT64: z_q *= W4096^{bq}; store H[q][b][T][c] to ws.
__global__ __launch_bounds__(256, 2)
void fft64_col_a(const float* __restrict__ Y, float* __restrict__ ws) {
    const int c = threadIdx.x & 63;
    const int w = threadIdx.x >> 6;
    const int b = blockIdx.x * 4 + w;       // 0..63
    const int T = blockIdx.y;               // 0..31
    const int ca = T * 128 + c;
    const int cb = ca + 64;

    FOR64(DECLZ)

#define LOADI(i) { \
        constexpr int a_ = drev6c(i); \
        const int row = (a_ < 32) ? (128 * a_ + 2 * b) : (8191 - 128 * a_ - 2 * b); \
        const float* rp = Y + (size_t)row * L; \
        z##i = make_float2(rp[ca], rp[cb]); }
    FOR64(LOADI)
#undef LOADI

    FFT64_BODY()

    // mid twiddle: z_q *= e^{-2 pi i b q / 4096}; sincos anchor every 8
    const float ang = (float)b * -1.5339807878856412e-3f;     // -2pi b/4096
    float2 m1; __sincosf(ang, &m1.y, &m1.x);
    float2 wv;
#define MIDQ(q) { \
        if constexpr ((q & 7) == 0) { \
            if constexpr (q == 0) wv = make_float2(1.0f, 0.0f); \
            else __sincosf(ang * (float)q, &wv.y, &wv.x); \
        } \
        if constexpr (q != 0) z##q = cmul(z##q, wv); \
        wv = cmul(wv, m1); }
    FOR64(MIDQ)
#undef MIDQ

    float2* wp = reinterpret_cast<float2*>(ws) + (size_t)b * 2048 + (size_t)T * 64 + c;
#define STQ(q) wp[(size_t)q * 131072] = z##q;
    FOR64(STQ)
#undef STQ
}

// ---------------- K2b: column pass, step 2 ----------------
//   Aseq[b] = 0.5*(H[q][b] + conj(H[q'][b])*fac_b),  q'=(64-q)&63,
//   Bseq[b] = -0.5i*(H[q][b] - conj(H[q'][b])*fac_b),
//   fac_b = W64^b for q>=1, 1 for q==0.   F/G[64p+q] = FFT64_b{seq}[p].
// 4 waves/block = (A/B) x (q, 64-q) -> share H slices in L1.
__global__ __launch_bounds__(256, 2)
void fft64_col_b(const float* __restrict__ wsf, float* __restrict__ out) {
    const int c  = threadIdx.x & 63;
    const int w  = threadIdx.x >> 6;
    const int qa = blockIdx.x;              // 0..31
    const int T  = blockIdx.y;              // 0..31
    const int q  = (w < 2) ? qa : ((qa == 0) ? 32 : 64 - qa);
    const int isB = w & 1;
    const int qp = (q == 0) ? 0 : ((64 - q) & 63);   // hp==hq when self-paired

    const float2* wsc = reinterpret_cast<const float2*>(wsf);
    const float2* hq = wsc + (size_t)q  * 131072 + (size_t)T * 64 + c;
    const float2* hp = wsc + (size_t)qp * 131072 + (size_t)T * 64 + c;

    FOR64(DECLZ)

#define LOADB(i) { \
        constexpr int bb_ = drev6c(i); \
        float2 a0 = hq[(size_t)bb_ * 2048]; \
        float2 p0 = hp[(size_t)bb_ * 2048]; \
        float2 pc = make_float2(p0.x, -p0.y); \
        float2 mm = (q == 0) ? pc : cmul(pc, W64T<bb_>()); \
        if (!isB) { \
            z##i = make_float2(0.5f * (a0.x + mm.x), 0.5f * (a0.y + mm.y)); \
        } else { \
            float vx = a0.x - mm.x, vy = a0.y - mm.y; \
            z##i = make_float2(0.5f * vy, -0.5f * vx); } }
    FOR64(LOADB)
#undef LOADB

    FFT64_BODY()

    // expk epilogue: out[64p+q][col] = z_p.x*cos(th)+z_p.y*sin(th),
    // th = pi*(64p+q)/8192; anchor every 16 p, advance by e^{+i pi/128}.
    const int col = T * 128 + (isB ? 64 : 0) + c;
    float* op = out + col;
    const float qth = (float)q * 3.8349519697141029e-4f;      // pi*q/8192
    const float2 M = make_float2(0.99969881869620425f, 0.024541228522912288f);
    float2 e;
#define EPI(p) { \
        if constexpr ((p & 15) == 0) \
            __sincosf((float)(64 * p) * 3.8349519697141029e-4f + qth, &e.y, &e.x); \
        op[((size_t)(64 * p) + (size_t)q) * L] = z##p.x * e.x + z##p.y * e.y; \
        e = cmul(e, M); }
    FOR64(EPI)
#undef EPI
}

extern "C" void kernel_launch(void* const* d_in, const int* in_sizes, int n_in,
                              void* d_out, int out_size, void* d_ws, size_t ws_size,
                              hipStream_t stream) {
    const float* x = (const float*)d_in[0];
    float* out = (float*)d_out;
    float* ws  = (float*)d_ws;   // needs 64 MB

    dct_rows2_kernel<<<L / 2, 256, 0, stream>>>(x, out);        // rows: x -> Y(out)
    fft64_col_a<<<dim3(16, 32), 256, 0, stream>>>(out, ws);     // Y -> H(ws)
    fft64_col_b<<<dim3(32, 32), 256, 0, stream>>>(ws, out);     // H -> final(out)
}

// Round 12
// 115.941 us; speedup vs baseline: 1.3267x; 1.0210x over previous
//
#include <hip/hip_runtime.h>
#include <hip/hip_bf16.h>

// 2D DCT-II (4096x4096 fp32).  Round 11:
//   K1  = R4's dct_rows2 (row DCT, LDS FFT4096, 2 rows packed, 41 us)
//   K2a = column-pass step 1 (reg FFT64, mid-twiddle) -> ws
//   K2b = column-pass step 2 (conj-split before FFT, reg FFT64, expk) -> out
// R10 finding: VGPR_Count pinned at 80 even with 64 NAMED float2 regs ->
// on gfx950's unified RF the allocator is keeping FFT state in AGPRs and
// ping-ponging v_accvgpr_read/write around every butterfly (launch_bounds
// (256,2) caps total regs at 256; arch split landed at 80).  This round:
// __launch_bounds__(256, 1) on K2a/K2b -> 512-reg budget -> FFT state in
// real arch VGPRs, loads pipeline deeply.  Everything else unchanged.
// Plan: K1(x->out) ; K2a(out->ws) ; K2b(ws->out).  d_ws needs 64 MB.

#define L 4096

__device__ __host__ constexpr int drev6c(int i) {
    return ((i & 3) << 4) | (i & 12) | ((i >> 4) & 3);
}

__device__ __forceinline__ int SWZ(int e) {
    return e ^ (((e >> 4) ^ (e >> 8)) & 15);
}

__device__ __forceinline__ int digitrev12(int n) {
    int r = 0;
#pragma unroll
    for (int i = 0; i < 6; ++i) { r = (r << 2) | (n & 3); n >>= 2; }
    return r;
}

__device__ __forceinline__ float2 cmul(float2 a, float2 b) {
    return make_float2(a.x * b.x - a.y * b.y, a.x * b.y + a.y * b.x);
}

__device__ __forceinline__ void bfly4(float2& x0, float2& x1, float2& x2, float2& x3) {
    float t0x = x0.x + x2.x, t0y = x0.y + x2.y;
    float t1x = x0.x - x2.x, t1y = x0.y - x2.y;
    float t2x = x1.x + x3.x, t2y = x1.y + x3.y;
    float t3x = x1.x - x3.x, t3y = x1.y - x3.y;
    x0 = make_float2(t0x + t2x, t0y + t2y);
    x1 = make_float2(t1x + t3y, t1y - t3x);   // t1 + (-i)*t3
    x2 = make_float2(t0x - t2x, t0y - t2y);
    x3 = make_float2(t1x - t3y, t1y + t3x);   // t1 + (+i)*t3
}

// e^{-2*pi*i*M/64} as compile-time literals.
template <int M>
__device__ __forceinline__ float2 W64T() {
    constexpr float C[17] = {1.f, 0.995184726672197f, 0.980785280403230f,
        0.956940335732209f, 0.923879532511287f, 0.881921264348355f,
        0.831469612302545f, 0.773010453362737f, 0.707106781186548f,
        0.634393284163645f, 0.555570233019602f, 0.471396736825998f,
        0.382683432365090f, 0.290284677254462f, 0.195090322016128f,
        0.098017140329561f, 0.f};
    constexpr int m = M & 63;
    constexpr float c = (m <= 16) ?  C[m]
                      : (m <= 32) ? -C[32 - m]
                      : (m <= 48) ? -C[m - 32]
                      :              C[64 - m];
    constexpr float s = (m <= 16) ?  C[16 - m]
                      : (m <= 32) ?  C[m - 16]
                      : (m <= 48) ? -C[48 - m]
                      :             -C[m - 48];
    return make_float2(c, -s);
}

// ---- X-macro plumbing: 64 named float2 registers ----
#define FOR64(X) X(0) X(1) X(2) X(3) X(4) X(5) X(6) X(7) X(8) X(9) X(10) X(11) \
  X(12) X(13) X(14) X(15) X(16) X(17) X(18) X(19) X(20) X(21) X(22) X(23) \
  X(24) X(25) X(26) X(27) X(28) X(29) X(30) X(31) X(32) X(33) X(34) X(35) \
  X(36) X(37) X(38) X(39) X(40) X(41) X(42) X(43) X(44) X(45) X(46) X(47) \
  X(48) X(49) X(50) X(51) X(52) X(53) X(54) X(55) X(56) X(57) X(58) X(59) \
  X(60) X(61) X(62) X(63)

#define DECLZ(i) float2 z##i;

#define B4(i0,i1,i2,i3) bfly4(z##i0, z##i1, z##i2, z##i3);
#define TB4(i0,i1,i2,i3,w) { \
    z##i1 = cmul(z##i1, W64T<(w)>());     \
    z##i2 = cmul(z##i2, W64T<2*(w)>());   \
    z##i3 = cmul(z##i3, W64T<3*(w)>());   \
    bfly4(z##i0, z##i1, z##i2, z##i3); }

// In-register FFT64 on named regs z0..z63.  Input: z_i = v[drev6(i)]
// (callers fold the digit reversal into their loads).  Output: z_q = V[q].
#define FFT64_BODY() \
  /* stage 0 (radix-4, Q=1) */ \
  B4(0,1,2,3)     B4(4,5,6,7)     B4(8,9,10,11)   B4(12,13,14,15) \
  B4(16,17,18,19) B4(20,21,22,23) B4(24,25,26,27) B4(28,29,30,31) \
  B4(32,33,34,35) B4(36,37,38,39) B4(40,41,42,43) B4(44,45,46,47) \
  B4(48,49,50,51) B4(52,53,54,55) B4(56,57,58,59) B4(60,61,62,63) \
  /* stage 1 (Q=4): base=16g+j, twiddle W64^{4j} */ \
  B4(0,4,8,12)        B4(16,20,24,28)      B4(32,36,40,44)      B4(48,52,56,60) \
  TB4(1,5,9,13,4)     TB4(17,21,25,29,4)   TB4(33,37,41,45,4)   TB4(49,53,57,61,4) \
  TB4(2,6,10,14,8)    TB4(18,22,26,30,8)   TB4(34,38,42,46,8)   TB4(50,54,58,62,8) \
  TB4(3,7,11,15,12)   TB4(19,23,27,31,12)  TB4(35,39,43,47,12)  TB4(51,55,59,63,12) \
  /* stage 2 (Q=16): j, j+16, j+32, j+48, twiddle W64^{j} */ \
  B4(0,16,32,48) \
  TB4(1,17,33,49,1)   TB4(2,18,34,50,2)    TB4(3,19,35,51,3)    TB4(4,20,36,52,4) \
  TB4(5,21,37,53,5)   TB4(6,22,38,54,6)    TB4(7,23,39,55,7)    TB4(8,24,40,56,8) \
  TB4(9,25,41,57,9)   TB4(10,26,42,58,10)  TB4(11,27,43,59,11)  TB4(12,28,44,60,12) \
  TB4(13,29,45,61,13) TB4(14,30,46,62,14)  TB4(15,31,47,63,15)

// ---------------- K1: row DCT (R4 structure, unchanged) ----------------

template <int Q>
__device__ __forceinline__ void stage_pair(float2* lds, int t) {
    const int j = t & (Q - 1);
    const int G = t / Q;
    const int base = G * 16 * Q + j;

    float2 v[4][4];
#pragma unroll
    for (int b = 0; b < 4; ++b)
#pragma unroll
        for (int a = 0; a < 4; ++a)
            v[a][b] = lds[SWZ(base + (a + 4 * b) * Q)];

    if (Q > 1) {
        float c1, s1;
        __sincosf((float)j * (-6.2831853071795864769f / (4.0f * (float)Q)), &s1, &c1);
        float2 w1 = make_float2(c1, s1);
        float2 w2 = cmul(w1, w1);
        float2 w3 = cmul(w2, w1);
#pragma unroll
        for (int b = 0; b < 4; ++b) {
            v[1][b] = cmul(v[1][b], w1);
            v[2][b] = cmul(v[2][b], w2);
            v[3][b] = cmul(v[3][b], w3);
        }
    }
#pragma unroll
    for (int b = 0; b < 4; ++b) bfly4(v[0][b], v[1][b], v[2][b], v[3][b]);

    float2 u;
    if (Q == 1) {
        u = make_float2(1.0f, 0.0f);
    } else {
        float cu, su;
        __sincosf((float)j * (-6.2831853071795864769f / (16.0f * (float)Q)), &su, &cu);
        u = make_float2(cu, su);
    }
    const float2 E = make_float2(0.92387953251128674f, -0.38268343236508977f);
    float2 w = u;
#pragma unroll
    for (int a = 0; a < 4; ++a) {
        if (!(Q == 1 && a == 0)) {
            float2 W2 = cmul(w, w);
            float2 W3 = cmul(W2, w);
            v[a][1] = cmul(v[a][1], w);
            v[a][2] = cmul(v[a][2], W2);
            v[a][3] = cmul(v[a][3], W3);
        }
        bfly4(v[a][0], v[a][1], v[a][2], v[a][3]);
        if (a < 3) w = cmul(w, E);
    }

#pragma unroll
    for (int b = 0; b < 4; ++b)
#pragma unroll
        for (int a = 0; a < 4; ++a)
            lds[SWZ(base + (a + 4 * b) * Q)] = v[a][b];
}

__global__ __launch_bounds__(256)
void dct_rows2_kernel(const float* __restrict__ in, float* __restrict__ out) {
    __shared__ float2 lds[L];   // 32 KB

    const int r0 = blockIdx.x * 2;
    const int t = threadIdx.x;
    const float* rowA = in + (size_t)r0 * L;
    const float* rowB = rowA + L;

#pragma unroll
    for (int w = 0; w < 8; ++w) {
        int n = w * 256 + t;
        float2 fa = *reinterpret_cast<const float2*>(&rowA[2 * n]);
        float2 fb = *reinterpret_cast<const float2*>(&rowB[2 * n]);
        int p = digitrev12(n);
        lds[SWZ(p)]        = make_float2(fa.x, fb.x);
        lds[SWZ(4095 - p)] = make_float2(fa.y, fb.y);
    }
    __syncthreads();

    stage_pair<1>(lds, t);
    __syncthreads();
    stage_pair<16>(lds, t);
    __syncthreads();
    stage_pair<256>(lds, t);
    __syncthreads();

    float* outA = out + (size_t)r0 * L;
    float* outB = outA + L;
#pragma unroll
    for (int w = 0; w < 16; ++w) {
        int k = w * 256 + t;
        float2 Zk = lds[SWZ(k)];
        int m = (L - k) & (L - 1);
        float2 Zm = lds[SWZ(m)];

        float vax = 0.5f * (Zk.x + Zm.x);
        float vay = 0.5f * (Zk.y - Zm.y);
        float vbx = 0.5f * (Zk.y + Zm.y);
        float vby = 0.5f * (Zm.x - Zk.x);

        float th = (float)k * 3.8349519697141029e-4f;   // pi/8192
        float sk, ck;
        __sincosf(th, &sk, &ck);
        outA[k] = vax * ck + vay * sk;
        outB[k] = vbx * ck + vby * sk;
    }
}

// ---------------- K2a: column pass, step 1 ----------------
// Per wave: fixed b.  z_i = v[64*drev6(i)+b][col] (coalesced 512B reads).
// After FFT64: z_q *= W4096^{bq}; store H[q][b][T][c] to ws.
__global__ __launch_bounds__(256, 1)
void fft64_col_a(const float* __restrict__ Y, float* __restrict__ ws) {
    const int c = threadIdx.x & 63;
    const int w = threadIdx.x >> 6;
    const int b = blockIdx.x * 4 + w;       // 0..63
    const int T = blockIdx.y;               // 0..31
    const int ca = T * 128 + c;
    const int cb = ca + 64;

    FOR64(DECLZ)

#define LOADI(i) { \
        constexpr int a_ = drev6c(i); \
        const int row = (a_ < 32) ? (128 * a_ + 2 * b) : (8191 - 128 * a_ - 2 * b); \
        const float* rp = Y + (size_t)row * L; \
        z##i = make_float2(rp[ca], rp[cb]); }
    FOR64(LOADI)
#undef LOADI

    FFT64_BODY()

    // mid twiddle: z_q *= e^{-2 pi i b q / 4096}; sincos anchor every 8
    const float ang = (float)b * -1.5339807878856412e-3f;     // -2pi b/4096
    float2 m1; __sincosf(ang, &m1.y, &m1.x);
    float2 wv;
#define MIDQ(q) { \
        if constexpr ((q & 7) == 0) { \
            if constexpr (q == 0) wv = make_float2(1.0f, 0.0f); \
            else __sincosf(ang * (float)q, &wv.y, &wv.x); \
        } \
        if constexpr (q != 0) z##q = cmul(z##q, wv); \
        wv = cmul(wv, m1); }
    FOR64(MIDQ)
#undef MIDQ

    float2* wp = reinterpret_cast<float2*>(ws) + (size_t)b * 2048 + (size_t)T * 64 + c;
#define STQ(q) wp[(size_t)q * 131072] = z##q;
    FOR64(STQ)
#undef STQ
}

// ---------------- K2b: column pass, step 2 ----------------
//   Aseq[b] = 0.5*(H[q][b] + conj(H[q'][b])*fac_b),  q'=(64-q)&63,
//   Bseq[b] = -0.5i*(H[q][b] - conj(H[q'][b])*fac_b),
//   fac_b = W64^b for q>=1, 1 for q==0.   F/G[64p+q] = FFT64_b{seq}[p].
// 4 waves/block = (A/B) x (q, 64-q) -> share H slices in L1.
__global__ __launch_bounds__(256, 1)
void fft64_col_b(const float* __restrict__ wsf, float* __restrict__ out) {
    const int c  = threadIdx.x & 63;
    const int w  = threadIdx.x >> 6;
    const int qa = blockIdx.x;              // 0..31
    const int T  = blockIdx.y;              // 0..31
    const int q  = (w < 2) ? qa : ((qa == 0) ? 32 : 64 - qa);
    const int isB = w & 1;
    const int qp = (q == 0) ? 0 : ((64 - q) & 63);   // hp==hq when self-paired

    const float2* wsc = reinterpret_cast<const float2*>(wsf);
    const float2* hq = wsc + (size_t)q  * 131072 + (size_t)T * 64 + c;
    const float2* hp = wsc + (size_t)qp * 131072 + (size_t)T * 64 + c;

    FOR64(DECLZ)

#define LOADB(i) { \
        constexpr int bb_ = drev6c(i); \
        float2 a0 = hq[(size_t)bb_ * 2048]; \
        float2 p0 = hp[(size_t)bb_ * 2048]; \
        float2 pc = make_float2(p0.x, -p0.y); \
        float2 mm = (q == 0) ? pc : cmul(pc, W64T<bb_>()); \
        if (!isB) { \
            z##i = make_float2(0.5f * (a0.x + mm.x), 0.5f * (a0.y + mm.y)); \
        } else { \
            float vx = a0.x - mm.x, vy = a0.y - mm.y; \
            z##i = make_float2(0.5f * vy, -0.5f * vx); } }
    FOR64(LOADB)
#undef LOADB

    FFT64_BODY()

    // expk epilogue: out[64p+q][col] = z_p.x*cos(th)+z_p.y*sin(th),
    // th = pi*(64p+q)/8192; anchor every 16 p, advance by e^{+i pi/128}.
    const int col = T * 128 + (isB ? 64 : 0) + c;
    float* op = out + col;
    const float qth = (float)q * 3.8349519697141029e-4f;      // pi*q/8192
    const float2 M = make_float2(0.99969881869620425f, 0.024541228522912288f);
    float2 e;
#define EPI(p) { \
        if constexpr ((p & 15) == 0) \
            __sincosf((float)(64 * p) * 3.8349519697141029e-4f + qth, &e.y, &e.x); \
        op[((size_t)(64 * p) + (size_t)q) * L] = z##p.x * e.x + z##p.y * e.y; \
        e = cmul(e, M); }
    FOR64(EPI)
#undef EPI
}

extern "C" void kernel_launch(void* const* d_in, const int* in_sizes, int n_in,
                              void* d_out, int out_size, void* d_ws, size_t ws_size,
                              hipStream_t stream) {
    const float* x = (const float*)d_in[0];
    float* out = (float*)d_out;
    float* ws  = (float*)d_ws;   // needs 64 MB

    dct_rows2_kernel<<<L / 2, 256, 0, stream>>>(x, out);        // rows: x -> Y(out)
    fft64_col_a<<<dim3(16, 32), 256, 0, stream>>>(out, ws);     // Y -> H(ws)
    fft64_col_b<<<dim3(32, 32), 256, 0, stream>>>(ws, out);     // H -> final(out)
}

// Round 13
// 91.529 us; speedup vs baseline: 1.6806x; 1.2667x over previous
//
#include <hip/hip_runtime.h>
#include <hip/hip_bf16.h>

// 2D DCT-II (4096x4096 fp32).  Round 12:
//   K1  = R4's dct_rows2 (row DCT, LDS FFT4096, 2 rows packed, 41 us)
//   K2a = column-pass step 1 (reg FFT64 per wave, mid-twiddle) -> ws  [R12]
//   K2b = NEW cooperative column-pass step 2: FFT64 = FFT8 x FFT8 with an
//         8x8-per-column LDS transpose.  8 float2 FFT state per thread
//         (K1's proven regime) -- no AGPR ping-pong.  4 roles (q,q')x(A,B)
//         sequential in-block, one load set -> ws read once total.
// Plan: K1(x->out) ; K2a(out->ws) ; K2b(ws->out).  d_ws needs 64 MB.

#define L 4096

__device__ __host__ constexpr int drev6c(int i) {
    return ((i & 3) << 4) | (i & 12) | ((i >> 4) & 3);
}

__device__ __forceinline__ int SWZ(int e) {
    return e ^ (((e >> 4) ^ (e >> 8)) & 15);
}

__device__ __forceinline__ int digitrev12(int n) {
    int r = 0;
#pragma unroll
    for (int i = 0; i < 6; ++i) { r = (r << 2) | (n & 3); n >>= 2; }
    return r;
}

__device__ __forceinline__ float2 cmul(float2 a, float2 b) {
    return make_float2(a.x * b.x - a.y * b.y, a.x * b.y + a.y * b.x);
}

__device__ __forceinline__ void bfly4(float2& x0, float2& x1, float2& x2, float2& x3) {
    float t0x = x0.x + x2.x, t0y = x0.y + x2.y;
    float t1x = x0.x - x2.x, t1y = x0.y - x2.y;
    float t2x = x1.x + x3.x, t2y = x1.y + x3.y;
    float t3x = x1.x - x3.x, t3y = x1.y - x3.y;
    x0 = make_float2(t0x + t2x, t0y + t2y);
    x1 = make_float2(t1x + t3y, t1y - t3x);   // t1 + (-i)*t3
    x2 = make_float2(t0x - t2x, t0y - t2y);
    x3 = make_float2(t1x - t3y, t1y + t3x);   // t1 + (+i)*t3
}

// e^{-2*pi*i*M/64} as compile-time literals.
template <int M>
__device__ __forceinline__ float2 W64T() {
    constexpr float C[17] = {1.f, 0.995184726672197f, 0.980785280403230f,
        0.956940335732209f, 0.923879532511287f, 0.881921264348355f,
        0.831469612302545f, 0.773010453362737f, 0.707106781186548f,
        0.634393284163645f, 0.555570233019602f, 0.471396736825998f,
        0.382683432365090f, 0.290284677254462f, 0.195090322016128f,
        0.098017140329561f, 0.f};
    constexpr int m = M & 63;
    constexpr float c = (m <= 16) ?  C[m]
                      : (m <= 32) ? -C[32 - m]
                      : (m <= 48) ? -C[m - 32]
                      :              C[64 - m];
    constexpr float s = (m <= 16) ?  C[16 - m]
                      : (m <= 32) ?  C[m - 16]
                      : (m <= 48) ? -C[48 - m]
                      :             -C[m - 48];
    return make_float2(c, -s);
}

// ---- X-macro plumbing ----
#define FOR64(X) X(0) X(1) X(2) X(3) X(4) X(5) X(6) X(7) X(8) X(9) X(10) X(11) \
  X(12) X(13) X(14) X(15) X(16) X(17) X(18) X(19) X(20) X(21) X(22) X(23) \
  X(24) X(25) X(26) X(27) X(28) X(29) X(30) X(31) X(32) X(33) X(34) X(35) \
  X(36) X(37) X(38) X(39) X(40) X(41) X(42) X(43) X(44) X(45) X(46) X(47) \
  X(48) X(49) X(50) X(51) X(52) X(53) X(54) X(55) X(56) X(57) X(58) X(59) \
  X(60) X(61) X(62) X(63)
#define FOR8(X) X(0) X(1) X(2) X(3) X(4) X(5) X(6) X(7)

#define DECLZ(i) float2 z##i;

#define B4(i0,i1,i2,i3) bfly4(z##i0, z##i1, z##i2, z##i3);
#define TB4(i0,i1,i2,i3,w) { \
    z##i1 = cmul(z##i1, W64T<(w)>());     \
    z##i2 = cmul(z##i2, W64T<2*(w)>());   \
    z##i3 = cmul(z##i3, W64T<3*(w)>());   \
    bfly4(z##i0, z##i1, z##i2, z##i3); }

// In-register FFT64 on named regs z0..z63 (K2a).  Input z_i = v[drev6(i)].
#define FFT64_BODY() \
  B4(0,1,2,3)     B4(4,5,6,7)     B4(8,9,10,11)   B4(12,13,14,15) \
  B4(16,17,18,19) B4(20,21,22,23) B4(24,25,26,27) B4(28,29,30,31) \
  B4(32,33,34,35) B4(36,37,38,39) B4(40,41,42,43) B4(44,45,46,47) \
  B4(48,49,50,51) B4(52,53,54,55) B4(56,57,58,59) B4(60,61,62,63) \
  B4(0,4,8,12)        B4(16,20,24,28)      B4(32,36,40,44)      B4(48,52,56,60) \
  TB4(1,5,9,13,4)     TB4(17,21,25,29,4)   TB4(33,37,41,45,4)   TB4(49,53,57,61,4) \
  TB4(2,6,10,14,8)    TB4(18,22,26,30,8)   TB4(34,38,42,46,8)   TB4(50,54,58,62,8) \
  TB4(3,7,11,15,12)   TB4(19,23,27,31,12)  TB4(35,39,43,47,12)  TB4(51,55,59,63,12) \
  B4(0,16,32,48) \
  TB4(1,17,33,49,1)   TB4(2,18,34,50,2)    TB4(3,19,35,51,3)    TB4(4,20,36,52,4) \
  TB4(5,21,37,53,5)   TB4(6,22,38,54,6)    TB4(7,23,39,55,7)    TB4(8,24,40,56,8) \
  TB4(9,25,41,57,9)   TB4(10,26,42,58,10)  TB4(11,27,43,59,11)  TB4(12,28,44,60,12) \
  TB4(13,29,45,61,13) TB4(14,30,46,62,14)  TB4(15,31,47,63,15)

// 8-point DFT on named regs P0..P7, natural in -> natural out (DIT radix-2):
// E=FFT4(x0,x2,x4,x6), O=FFT4(x1,x3,x5,x7); X[k]=E[k]+W8^k O[k].
#define FFT8N(P) \
  bfly4(P##0, P##2, P##4, P##6); \
  bfly4(P##1, P##3, P##5, P##7); \
  { float2 e1_=P##2, e2_=P##4, e3_=P##6, o0_=P##1, o1_=P##3, o2_=P##5, o3_=P##7; \
    o1_ = cmul(o1_, make_float2(0.70710678118654752f, -0.70710678118654752f)); \
    o2_ = make_float2(o2_.y, -o2_.x); \
    o3_ = cmul(o3_, make_float2(-0.70710678118654752f, -0.70710678118654752f)); \
    float2 e0_=P##0; \
    P##0 = make_float2(e0_.x+o0_.x, e0_.y+o0_.y); \
    P##4 = make_float2(e0_.x-o0_.x, e0_.y-o0_.y); \
    P##1 = make_float2(e1_.x+o1_.x, e1_.y+o1_.y); \
    P##5 = make_float2(e1_.x-o1_.x, e1_.y-o1_.y); \
    P##2 = make_float2(e2_.x+o2_.x, e2_.y+o2_.y); \
    P##6 = make_float2(e2_.x-o2_.x, e2_.y-o2_.y); \
    P##3 = make_float2(e3_.x+o3_.x, e3_.y+o3_.y); \
    P##7 = make_float2(e3_.x-o3_.x, e3_.y-o3_.y); }

// ---------------- K1: row DCT (R4 structure, unchanged) ----------------

template <int Q>
__device__ __forceinline__ void stage_pair(float2* lds, int t) {
    const int j = t & (Q - 1);
    const int G = t / Q;
    const int base = G * 16 * Q + j;

    float2 v[4][4];
#pragma unroll
    for (int b = 0; b < 4; ++b)
#pragma unroll
        for (int a = 0; a < 4; ++a)
            v[a][b] = lds[SWZ(base + (a + 4 * b) * Q)];

    if (Q > 1) {
        float c1, s1;
        __sincosf((float)j * (-6.2831853071795864769f / (4.0f * (float)Q)), &s1, &c1);
        float2 w1 = make_float2(c1, s1);
        float2 w2 = cmul(w1, w1);
        float2 w3 = cmul(w2, w1);
#pragma unroll
        for (int b = 0; b < 4; ++b) {
            v[1][b] = cmul(v[1][b], w1);
            v[2][b] = cmul(v[2][b], w2);
            v[3][b] = cmul(v[3][b], w3);
        }
    }
#pragma unroll
    for (int b = 0; b < 4; ++b) bfly4(v[0][b], v[1][b], v[2][b], v[3][b]);

    float2 u;
    if (Q == 1) {
        u = make_float2(1.0f, 0.0f);
    } else {
        float cu, su;
        __sincosf((float)j * (-6.2831853071795864769f / (16.0f * (float)Q)), &su, &cu);
        u = make_float2(cu, su);
    }
    const float2 E = make_float2(0.92387953251128674f, -0.38268343236508977f);
    float2 w = u;
#pragma unroll
    for (int a = 0; a < 4; ++a) {
        if (!(Q == 1 && a == 0)) {
            float2 W2 = cmul(w, w);
            float2 W3 = cmul(W2, w);
            v[a][1] = cmul(v[a][1], w);
            v[a][2] = cmul(v[a][2], W2);
            v[a][3] = cmul(v[a][3], W3);
        }
        bfly4(v[a][0], v[a][1], v[a][2], v[a][3]);
        if (a < 3) w = cmul(w, E);
    }

#pragma unroll
    for (int b = 0; b < 4; ++b)
#pragma unroll
        for (int a = 0; a < 4; ++a)
            lds[SWZ(base + (a + 4 * b) * Q)] = v[a][b];
}

__global__ __launch_bounds__(256)
void dct_rows2_kernel(const float* __restrict__ in, float* __restrict__ out) {
    __shared__ float2 lds[L];   // 32 KB

    const int r0 = blockIdx.x * 2;
    const int t = threadIdx.x;
    const float* rowA = in + (size_t)r0 * L;
    const float* rowB = rowA + L;

#pragma unroll
    for (int w = 0; w < 8; ++w) {
        int n = w * 256 + t;
        float2 fa = *reinterpret_cast<const float2*>(&rowA[2 * n]);
        float2 fb = *reinterpret_cast<const float2*>(&rowB[2 * n]);
        int p = digitrev12(n);
        lds[SWZ(p)]        = make_float2(fa.x, fb.x);
        lds[SWZ(4095 - p)] = make_float2(fa.y, fb.y);
    }
    __syncthreads();

    stage_pair<1>(lds, t);
    __syncthreads();
    stage_pair<16>(lds, t);
    __syncthreads();
    stage_pair<256>(lds, t);
    __syncthreads();

    float* outA = out + (size_t)r0 * L;
    float* outB = outA + L;
#pragma unroll
    for (int w = 0; w < 16; ++w) {
        int k = w * 256 + t;
        float2 Zk = lds[SWZ(k)];
        int m = (L - k) & (L - 1);
        float2 Zm = lds[SWZ(m)];

        float vax = 0.5f * (Zk.x + Zm.x);
        float vay = 0.5f * (Zk.y - Zm.y);
        float vbx = 0.5f * (Zk.y + Zm.y);
        float vby = 0.5f * (Zm.x - Zk.x);

        float th = (float)k * 3.8349519697141029e-4f;   // pi/8192
        float sk, ck;
        __sincosf(th, &sk, &ck);
        outA[k] = vax * ck + vay * sk;
        outB[k] = vbx * ck + vby * sk;
    }
}

// ---------------- K2a: column pass, step 1 (R12, unchanged) ----------------
__global__ __launch_bounds__(256, 1)
void fft64_col_a(const float* __restrict__ Y, float* __restrict__ ws) {
    const int c = threadIdx.x & 63;
    const int w = threadIdx.x >> 6;
    const int b = blockIdx.x * 4 + w;       // 0..63
    const int T = blockIdx.y;               // 0..31
    const int ca = T * 128 + c;
    const int cb = ca + 64;

    FOR64(DECLZ)

#define LOADI(i) { \
        constexpr int a_ = drev6c(i); \
        const int row = (a_ < 32) ? (128 * a_ + 2 * b) : (8191 - 128 * a_ - 2 * b); \
        const float* rp = Y + (size_t)row * L; \
        z##i = make_float2(rp[ca], rp[cb]); }
    FOR64(LOADI)
#undef LOADI

    FFT64_BODY()

    const float ang = (float)b * -1.5339807878856412e-3f;     // -2pi b/4096
    float2 m1; __sincosf(ang, &m1.y, &m1.x);
    float2 wv;
#define MIDQ(q) { \
        if constexpr ((q & 7) == 0) { \
            if constexpr (q == 0) wv = make_float2(1.0f, 0.0f); \
            else __sincosf(ang * (float)q, &wv.y, &wv.x); \
        } \
        if constexpr (q != 0) z##q = cmul(z##q, wv); \
        wv = cmul(wv, m1); }
    FOR64(MIDQ)
#undef MIDQ

    float2* wp = reinterpret_cast<float2*>(ws) + (size_t)b * 2048 + (size_t)T * 64 + c;
#define STQ(q) wp[(size_t)q * 131072] = z##q;
    FOR64(STQ)
#undef STQ
}

// ---------------- K2b: cooperative column pass, step 2 ----------------
// FFT64 over b, split 8x8: b = 8u+v.  Thread (c, v) of a 512-thread block:
//   seq[u] from H[qr][8u+v], H[qp][8u+v]  (conj-split, R12-verified formula)
//   FFT8 over u -> G[k][v]; LDS transpose [vv][k][c]; twiddle W64^{vv*v};
//   FFT8 over vv -> Z[64(8a+v)+qr]; expk; store.
// 4 roles (q,A),(q,B),(q2,A),(q2,B) sequential, one load set.
__global__ __launch_bounds__(512)
void fft64_col_b2(const float* __restrict__ wsf, float* __restrict__ out) {
    __shared__ float2 xch[4096];            // [vv][k][c] = vv*512+k*64+c, 32 KB
    const int c  = threadIdx.x & 63;
    const int v  = threadIdx.x >> 6;        // 0..7
    const int qa = blockIdx.x;              // 0..31
    const int T  = blockIdx.y;              // 0..31
    const int q  = qa;
    const int q2 = (qa == 0) ? 32 : 64 - qa;
    const bool self0 = (qa == 0);           // both q and q2 self-paired

    const float2* wsc = reinterpret_cast<const float2*>(wsf);
    const size_t cbase = (size_t)T * 64 + c;

    // loads: ha[u] = H[q][8u+v], hp[u] = H[q2][8u+v]
#define LDH(u) \
    float2 ha##u = wsc[(size_t)q  * 131072 + (size_t)(8*u+v) * 2048 + cbase]; \
    float2 hp##u = wsc[(size_t)q2 * 131072 + (size_t)(8*u+v) * 2048 + cbase];
    FOR8(LDH)
#undef LDH

    // wv = e^{-2pi i v/64};  fac[u] = W64^{8u+v} = W64^{8u} * wv
    float2 wv; __sincosf((float)v * -0.09817477042468103f, &wv.y, &wv.x);
#define MKF(u) float2 fc##u = cmul(W64T<8*u>(), wv);
    FOR8(MKF)
#undef MKF

    const float2 STEP = make_float2(0.98078528040323045f, 0.19509032201612827f); // e^{+i pi/16}

    for (int r = 0; r < 4; ++r) {
        const int qr  = (r < 2) ? q : q2;
        const int isB = r & 1;
        const bool sw = (r >= 2);

        // build seq (g0..g7):  hh=H[qr][b], pp=H[qp(qr)][b]
#define MKSEQ(u) float2 g##u; { \
        float2 hh = sw ? hp##u : ha##u; \
        float2 pp = self0 ? hh : (sw ? ha##u : hp##u); \
        float2 cj = make_float2(pp.x, -pp.y); \
        float2 mm = (qr == 0) ? cj : cmul(cj, fc##u); \
        if (!isB) g##u = make_float2(0.5f * (hh.x + mm.x), 0.5f * (hh.y + mm.y)); \
        else      g##u = make_float2(0.5f * (hh.y - mm.y), -0.5f * (hh.x - mm.x)); }
        FOR8(MKSEQ)
#undef MKSEQ

        FFT8N(g)                            // G[k] over u -> g_k, k natural

        __syncthreads();                    // previous role's reads complete
#define WRX(k) xch[v * 512 + k * 64 + c] = g##k;
        FOR8(WRX)
#undef WRX
        __syncthreads();
#define RDX(vv) g##vv = xch[vv * 512 + v * 64 + c];
        FOR8(RDX)
#undef RDX

        // twiddle: g_vv *= W64^{vv * v}  (chain powers of wv)
        {
            float2 f = wv;
            g1 = cmul(g1, f); f = cmul(f, wv);
            g2 = cmul(g2, f); f = cmul(f, wv);
            g3 = cmul(g3, f); f = cmul(f, wv);
            g4 = cmul(g4, f); f = cmul(f, wv);
            g5 = cmul(g5, f); f = cmul(f, wv);
            g6 = cmul(g6, f); f = cmul(f, wv);
            g7 = cmul(g7, f);
        }

        FFT8N(g)                            // -> Z[64*(8a+v)+qr] in g_a

        // expk + store:  k = 512a + 64v + qr, col = T*128 + c (+64 if B)
        float2 e; __sincosf((float)(64 * v + qr) * 3.8349519697141029e-4f, &e.y, &e.x);
        const int colb = T * 128 + c + (isB ? 64 : 0);
#define EP(a2) { \
        out[(size_t)(512 * a2 + 64 * v + qr) * L + colb] = g##a2.x * e.x + g##a2.y * e.y; \
        e = cmul(e, STEP); }
        FOR8(EP)
#undef EP
    }
}

extern "C" void kernel_launch(void* const* d_in, const int* in_sizes, int n_in,
                              void* d_out, int out_size, void* d_ws, size_t ws_size,
                              hipStream_t stream) {
    const float* x = (const float*)d_in[0];
    float* out = (float*)d_out;
    float* ws  = (float*)d_ws;   // needs 64 MB

    dct_rows2_kernel<<<L / 2, 256, 0, stream>>>(x, out);        // rows: x -> Y(out)
    fft64_col_a<<<dim3(16, 32), 256, 0, stream>>>(out, ws);     // Y -> H(ws)
    fft64_col_b2<<<dim3(32, 32), 512, 0, stream>>>(ws, out);    // H -> final(out)
}

// Round 14
// 88.116 us; speedup vs baseline: 1.7457x; 1.0387x over previous
//
#include <hip/hip_runtime.h>
#include <hip/hip_bf16.h>

// 2D DCT-II (4096x4096 fp32).  Round 14:
//   K1  = row DCT (R4 LDS FFT4096, 2 rows packed) + chained expk epilogue
//   K2a = cooperative column step 1: FFT64 over a via FFT8xFFT8 (8 float2 /
//         thread, 1 LDS round trip), mid-twiddle, -> ws
//   K2b = cooperative column step 2 (R13) + DOUBLE-BUFFERED LDS: barrier
//         count 8 -> 4 (role r writes buf[r&1]; role r-1's barrier already
//         orders it after role r-2's reads).
// Design rule from R7-R13: keep <=16 float2 live per thread (K1 regime);
// 64-float2-per-thread forms get shadowed into AGPRs (VGPR_Count 80 +
// v_accvgpr ping-pong) regardless of code shape.
// Plan: K1(x->out) ; K2a(out->ws) ; K2b(ws->out).  d_ws needs 64 MB.

#define L 4096

__device__ __forceinline__ int SWZ(int e) {
    return e ^ (((e >> 4) ^ (e >> 8)) & 15);
}

__device__ __forceinline__ float2 cmul(float2 a, float2 b) {
    return make_float2(a.x * b.x - a.y * b.y, a.x * b.y + a.y * b.x);
}

__device__ __forceinline__ void bfly4(float2& x0, float2& x1, float2& x2, float2& x3) {
    float t0x = x0.x + x2.x, t0y = x0.y + x2.y;
    float t1x = x0.x - x2.x, t1y = x0.y - x2.y;
    float t2x = x1.x + x3.x, t2y = x1.y + x3.y;
    float t3x = x1.x - x3.x, t3y = x1.y - x3.y;
    x0 = make_float2(t0x + t2x, t0y + t2y);
    x1 = make_float2(t1x + t3y, t1y - t3x);   // t1 + (-i)*t3
    x2 = make_float2(t0x - t2x, t0y - t2y);
    x3 = make_float2(t1x - t3y, t1y + t3x);   // t1 + (+i)*t3
}

// e^{-2*pi*i*M/64} as compile-time literals.
template <int M>
__device__ __forceinline__ float2 W64T() {
    constexpr float C[17] = {1.f, 0.995184726672197f, 0.980785280403230f,
        0.956940335732209f, 0.923879532511287f, 0.881921264348355f,
        0.831469612302545f, 0.773010453362737f, 0.707106781186548f,
        0.634393284163645f, 0.555570233019602f, 0.471396736825998f,
        0.382683432365090f, 0.290284677254462f, 0.195090322016128f,
        0.098017140329561f, 0.f};
    constexpr int m = M & 63;
    constexpr float c = (m <= 16) ?  C[m]
                      : (m <= 32) ? -C[32 - m]
                      : (m <= 48) ? -C[m - 32]
                      :              C[64 - m];
    constexpr float s = (m <= 16) ?  C[16 - m]
                      : (m <= 32) ?  C[m - 16]
                      : (m <= 48) ? -C[48 - m]
                      :             -C[m - 48];
    return make_float2(c, -s);
}

#define FOR8(X) X(0) X(1) X(2) X(3) X(4) X(5) X(6) X(7)

// 8-point DFT on named regs P0..P7, natural in -> natural out (DIT):
// E=FFT4(x0,x2,x4,x6), O=FFT4(x1,x3,x5,x7); X[k]=E[k]+W8^k O[k].
#define FFT8N(P) \
  bfly4(P##0, P##2, P##4, P##6); \
  bfly4(P##1, P##3, P##5, P##7); \
  { float2 e1_=P##2, e2_=P##4, e3_=P##6, o0_=P##1, o1_=P##3, o2_=P##5, o3_=P##7; \
    o1_ = cmul(o1_, make_float2(0.70710678118654752f, -0.70710678118654752f)); \
    o2_ = make_float2(o2_.y, -o2_.x); \
    o3_ = cmul(o3_, make_float2(-0.70710678118654752f, -0.70710678118654752f)); \
    float2 e0_=P##0; \
    P##0 = make_float2(e0_.x+o0_.x, e0_.y+o0_.y); \
    P##4 = make_float2(e0_.x-o0_.x, e0_.y-o0_.y); \
    P##1 = make_float2(e1_.x+o1_.x, e1_.y+o1_.y); \
    P##5 = make_float2(e1_.x-o1_.x, e1_.y-o1_.y); \
    P##2 = make_float2(e2_.x+o2_.x, e2_.y+o2_.y); \
    P##6 = make_float2(e2_.x-o2_.x, e2_.y-o2_.y); \
    P##3 = make_float2(e3_.x+o3_.x, e3_.y+o3_.y); \
    P##7 = make_float2(e3_.x-o3_.x, e3_.y-o3_.y); }

// ---------------- K1: row DCT ----------------

template <int Q>
__device__ __forceinline__ void stage_pair(float2* lds, int t) {
    const int j = t & (Q - 1);
    const int G = t / Q;
    const int base = G * 16 * Q + j;

    float2 v[4][4];
#pragma unroll
    for (int b = 0; b < 4; ++b)
#pragma unroll
        for (int a = 0; a < 4; ++a)
            v[a][b] = lds[SWZ(base + (a + 4 * b) * Q)];

    if (Q > 1) {
        float c1, s1;
        __sincosf((float)j * (-6.2831853071795864769f / (4.0f * (float)Q)), &s1, &c1);
        float2 w1 = make_float2(c1, s1);
        float2 w2 = cmul(w1, w1);
        float2 w3 = cmul(w2, w1);
#pragma unroll
        for (int b = 0; b < 4; ++b) {
            v[1][b] = cmul(v[1][b], w1);
            v[2][b] = cmul(v[2][b], w2);
            v[3][b] = cmul(v[3][b], w3);
        }
    }
#pragma unroll
    for (int b = 0; b < 4; ++b) bfly4(v[0][b], v[1][b], v[2][b], v[3][b]);

    float2 u;
    if (Q == 1) {
        u = make_float2(1.0f, 0.0f);
    } else {
        float cu, su;
        __sincosf((float)j * (-6.2831853071795864769f / (16.0f * (float)Q)), &su, &cu);
        u = make_float2(cu, su);
    }
    const float2 E = make_float2(0.92387953251128674f, -0.38268343236508977f);
    float2 w = u;
#pragma unroll
    for (int a = 0; a < 4; ++a) {
        if (!(Q == 1 && a == 0)) {
            float2 W2 = cmul(w, w);
            float2 W3 = cmul(W2, w);
            v[a][1] = cmul(v[a][1], w);
            v[a][2] = cmul(v[a][2], W2);
            v[a][3] = cmul(v[a][3], W3);
        }
        bfly4(v[a][0], v[a][1], v[a][2], v[a][3]);
        if (a < 3) w = cmul(w, E);
    }

#pragma unroll
    for (int b = 0; b < 4; ++b)
#pragma unroll
        for (int a = 0; a < 4; ++a)
            lds[SWZ(base + (a + 4 * b) * Q)] = v[a][b];
}

__global__ __launch_bounds__(256)
void dct_rows2_kernel(const float* __restrict__ in, float* __restrict__ out) {
    __shared__ float2 lds[L];   // 32 KB

    const int r0 = blockIdx.x * 2;
    const int t = threadIdx.x;
    const float* rowA = in + (size_t)r0 * L;
    const float* rowB = rowA + L;

    // digitrev12(w*256+t) = (revT4(t)<<4) | ((w&3)<<2) | (w>>2)
    const int revT4 = ((t & 3) << 6) | ((t & 12) << 2) | ((t >> 2) & 12) | ((t >> 6) & 3);

#pragma unroll
    for (int w = 0; w < 8; ++w) {
        int n = w * 256 + t;
        float2 fa = *reinterpret_cast<const float2*>(&rowA[2 * n]);
        float2 fb = *reinterpret_cast<const float2*>(&rowB[2 * n]);
        int p = (revT4 << 4) | ((w & 3) << 2) | (w >> 2);
        lds[SWZ(p)]        = make_float2(fa.x, fb.x);
        lds[SWZ(4095 - p)] = make_float2(fa.y, fb.y);
    }
    __syncthreads();

    stage_pair<1>(lds, t);
    __syncthreads();
    stage_pair<16>(lds, t);
    __syncthreads();
    stage_pair<256>(lds, t);
    __syncthreads();

    float* outA = out + (size_t)r0 * L;
    float* outB = outA + L;

    // expk: k = w*256+t -> theta step pi/32 per w; 1 sincos + 15 chained cmul
    float2 e;
    __sincosf((float)t * 3.8349519697141029e-4f, &e.y, &e.x);   // pi*t/8192
    const float2 ST = make_float2(0.99518472667219693f, 0.09801714032956060f); // e^{i pi/32}
#pragma unroll
    for (int w = 0; w < 16; ++w) {
        int k = w * 256 + t;
        float2 Zk = lds[SWZ(k)];
        int m = (L - k) & (L - 1);
        float2 Zm = lds[SWZ(m)];

        float vax = 0.5f * (Zk.x + Zm.x);
        float vay = 0.5f * (Zk.y - Zm.y);
        float vbx = 0.5f * (Zk.y + Zm.y);
        float vby = 0.5f * (Zm.x - Zk.x);

        outA[k] = vax * e.x + vay * e.y;
        outB[k] = vbx * e.x + vby * e.y;
        e = cmul(e, ST);
    }
}

// ---------------- K2a: cooperative column pass, step 1 ----------------
// FFT64 over a (natural in/out via FFT8 x FFT8), per (b, col-tile T).
// Thread (c,v): g_u = v[64*(8u+v)+b][col]; FFT8(u) -> G[t][v]; LDS
// transpose t<->v; twiddle W64^{vv*v}; FFT8 -> Z[8s+v]; mid twiddle
// W4096^{b*q}; store H[q][b][T][c].
__global__ __launch_bounds__(512)
void fft64_col_a2(const float* __restrict__ Y, float* __restrict__ ws) {
    __shared__ float2 xch[4096];            // [v][t][c], 32 KB
    const int c = threadIdx.x & 63;
    const int v = threadIdx.x >> 6;         // 0..7
    const int b = blockIdx.x;               // 0..63
    const int T = blockIdx.y;               // 0..31
    const int ca = T * 128 + c;
    const int cb = ca + 64;

    // loads: row = sigma(64*(8u+v)+b); 8u+v<32 <=> u<4
#define LDA(u) float2 g##u; { \
        const int aa = 8 * u + v; \
        const int row = (u < 4) ? (128 * aa + 2 * b) : (8191 - 128 * aa - 2 * b); \
        const float* rp = Y + (size_t)row * L; \
        g##u = make_float2(rp[ca], rp[cb]); }
    FOR8(LDA)
#undef LDA

    FFT8N(g)                                // over u -> G[t][v] in g_t

#define WRA(t) xch[v * 512 + t * 64 + c] = g##t;
    FOR8(WRA)
#undef WRA
    __syncthreads();
#define RDA(vv) g##vv = xch[vv * 512 + v * 64 + c];
    FOR8(RDA)
#undef RDA

    // twiddle: g_vv *= W64^{vv*v}
    float2 wv; __sincosf((float)v * -0.09817477042468103f, &wv.y, &wv.x); // -2pi v/64
    {
        float2 f = wv;
        g1 = cmul(g1, f); f = cmul(f, wv);
        g2 = cmul(g2, f); f = cmul(f, wv);
        g3 = cmul(g3, f); f = cmul(f, wv);
        g4 = cmul(g4, f); f = cmul(f, wv);
        g5 = cmul(g5, f); f = cmul(f, wv);
        g6 = cmul(g6, f); f = cmul(f, wv);
        g7 = cmul(g7, f);
    }

    FFT8N(g)                                // -> Z[q], q = 8s+v, in g_s

    // mid twiddle: z_q *= e^{-2pi i b q/4096}, q = 8s+v:
    // anchor e^{-2pi i b v/4096}, chain step e^{-2pi i 8b/4096}
    float2 mw, ms;
    __sincosf((float)(b * v) * -1.5339807878856412e-3f, &mw.y, &mw.x);
    __sincosf((float)b * -1.2271846303085130e-2f, &ms.y, &ms.x);   // -pi b/256
    float2* wp = reinterpret_cast<float2*>(ws) + (size_t)b * 2048 + (size_t)T * 64 + c;
#define STA(s) { \
        g##s = cmul(g##s, mw); \
        wp[(size_t)(8 * s + v) * 131072] = g##s; \
        mw = cmul(mw, ms); }
    FOR8(STA)
#undef STA
}

// ---------------- K2b: cooperative column pass, step 2 ----------------
// (R13 structure, double-buffered LDS: 4 barriers instead of 8.)
__global__ __launch_bounds__(512)
void fft64_col_b2(const float* __restrict__ wsf, float* __restrict__ out) {
    __shared__ float2 xch[8192];            // two 32 KB buffers
    const int c  = threadIdx.x & 63;
    const int v  = threadIdx.x >> 6;        // 0..7
    const int qa = blockIdx.x;              // 0..31
    const int T  = blockIdx.y;              // 0..31
    const int q  = qa;
    const int q2 = (qa == 0) ? 32 : 64 - qa;
    const bool self0 = (qa == 0);           // both q and q2 self-paired

    const float2* wsc = reinterpret_cast<const float2*>(wsf);
    const size_t cbase = (size_t)T * 64 + c;

#define LDH(u) \
    float2 ha##u = wsc[(size_t)q  * 131072 + (size_t)(8*u+v) * 2048 + cbase]; \
    float2 hp##u = wsc[(size_t)q2 * 131072 + (size_t)(8*u+v) * 2048 + cbase];
    FOR8(LDH)
#undef LDH

    float2 wv; __sincosf((float)v * -0.09817477042468103f, &wv.y, &wv.x);
#define MKF(u) float2 fc##u = cmul(W64T<8*u>(), wv);
    FOR8(MKF)
#undef MKF

    const float2 STEP = make_float2(0.98078528040323045f, 0.19509032201612827f); // e^{+i pi/16}

    for (int r = 0; r < 4; ++r) {
        const int qr  = (r < 2) ? q : q2;
        const int isB = r & 1;
        const bool sw = (r >= 2);
        const int buf = (r & 1) * 4096;

#define MKSEQ(u) float2 g##u; { \
        float2 hh = sw ? hp##u : ha##u; \
        float2 pp = self0 ? hh : (sw ? ha##u : hp##u); \
        float2 cj = make_float2(pp.x, -pp.y); \
        float2 mm = (qr == 0) ? cj : cmul(cj, fc##u); \
        if (!isB) g##u = make_float2(0.5f * (hh.x + mm.x), 0.5f * (hh.y + mm.y)); \
        else      g##u = make_float2(0.5f * (hh.y - mm.y), -0.5f * (hh.x - mm.x)); }
        FOR8(MKSEQ)
#undef MKSEQ

        FFT8N(g)                            // G[k] over u -> g_k

#define WRX(k) xch[buf + v * 512 + k * 64 + c] = g##k;
        FOR8(WRX)
#undef WRX
        __syncthreads();                    // the ONLY barrier per role
#define RDX(vv) g##vv = xch[buf + vv * 512 + v * 64 + c];
        FOR8(RDX)
#undef RDX

        {
            float2 f = wv;
            g1 = cmul(g1, f); f = cmul(f, wv);
            g2 = cmul(g2, f); f = cmul(f, wv);
            g3 = cmul(g3, f); f = cmul(f, wv);
            g4 = cmul(g4, f); f = cmul(f, wv);
            g5 = cmul(g5, f); f = cmul(f, wv);
            g6 = cmul(g6, f); f = cmul(f, wv);
            g7 = cmul(g7, f);
        }

        FFT8N(g)                            // -> Z[64*(8a+v)+qr] in g_a

        float2 e; __sincosf((float)(64 * v + qr) * 3.8349519697141029e-4f, &e.y, &e.x);
        const int colb = T * 128 + c + (isB ? 64 : 0);
#define EP(a2) { \
        out[(size_t)(512 * a2 + 64 * v + qr) * L + colb] = g##a2.x * e.x + g##a2.y * e.y; \
        e = cmul(e, STEP); }
        FOR8(EP)
#undef EP
    }
}

extern "C" void kernel_launch(void* const* d_in, const int* in_sizes, int n_in,
                              void* d_out, int out_size, void* d_ws, size_t ws_size,
                              hipStream_t stream) {
    const float* x = (const float*)d_in[0];
    float* out = (float*)d_out;
    float* ws  = (float*)d_ws;   // needs 64 MB

    dct_rows2_kernel<<<L / 2, 256, 0, stream>>>(x, out);        // rows: x -> Y(out)
    fft64_col_a2<<<dim3(64, 32), 512, 0, stream>>>(out, ws);    // Y -> H(ws)
    fft64_col_b2<<<dim3(32, 32), 512, 0, stream>>>(ws, out);    // H -> final(out)
}

// Round 15
// 79.949 us; speedup vs baseline: 1.9240x; 1.1022x over previous
//
#include <hip/hip_runtime.h>
#include <hip/hip_bf16.h>

// 2D DCT-II (4096x4096 fp32).  Round 15:
//   K1  = row DCT (R4 LDS FFT4096, 2 rows packed, chained expk)  [unchanged]
//   K2a = cooperative column step 1 (FFT8xFFT8, mid-twiddle) -> ws [unchanged]
//   K2b = REWRITTEN: linearity trick.  The 4 conj-split roles are combines of
//         just TWO FFT64s:  Gq=FFT_b(H[q]), Gq2=FFT_b(H[q2]);
//         F_A^{q}[p]  = 0.5 (Gq[p]  + conj(Gq2[63-p]))
//         F_B^{q}[p]  = -0.5i(Gq[p]  - conj(Gq2[63-p]))
//         F_A^{q2}[p] = 0.5 (Gq2[p] + conj(Gq [63-p]))   (+ qa==0 self-pair
//         F_B^{q2}[p] = -0.5i(Gq2[p] - conj(Gq [63-p]))    reflection variants)
//         -> half the FFT work of R14's 4-role form.
// Plan: K1(x->out) ; K2a(out->ws) ; K2b(ws->out).  d_ws needs 64 MB.

#define L 4096

__device__ __forceinline__ int SWZ(int e) {
    return e ^ (((e >> 4) ^ (e >> 8)) & 15);
}

__device__ __forceinline__ float2 cmul(float2 a, float2 b) {
    return make_float2(a.x * b.x - a.y * b.y, a.x * b.y + a.y * b.x);
}

__device__ __forceinline__ void bfly4(float2& x0, float2& x1, float2& x2, float2& x3) {
    float t0x = x0.x + x2.x, t0y = x0.y + x2.y;
    float t1x = x0.x - x2.x, t1y = x0.y - x2.y;
    float t2x = x1.x + x3.x, t2y = x1.y + x3.y;
    float t3x = x1.x - x3.x, t3y = x1.y - x3.y;
    x0 = make_float2(t0x + t2x, t0y + t2y);
    x1 = make_float2(t1x + t3y, t1y - t3x);   // t1 + (-i)*t3
    x2 = make_float2(t0x - t2x, t0y - t2y);
    x3 = make_float2(t1x - t3y, t1y + t3x);   // t1 + (+i)*t3
}

#define FOR8(X) X(0) X(1) X(2) X(3) X(4) X(5) X(6) X(7)

// 8-point DFT on named regs P0..P7, natural in -> natural out (DIT):
#define FFT8N(P) \
  bfly4(P##0, P##2, P##4, P##6); \
  bfly4(P##1, P##3, P##5, P##7); \
  { float2 e1_=P##2, e2_=P##4, e3_=P##6, o0_=P##1, o1_=P##3, o2_=P##5, o3_=P##7; \
    o1_ = cmul(o1_, make_float2(0.70710678118654752f, -0.70710678118654752f)); \
    o2_ = make_float2(o2_.y, -o2_.x); \
    o3_ = cmul(o3_, make_float2(-0.70710678118654752f, -0.70710678118654752f)); \
    float2 e0_=P##0; \
    P##0 = make_float2(e0_.x+o0_.x, e0_.y+o0_.y); \
    P##4 = make_float2(e0_.x-o0_.x, e0_.y-o0_.y); \
    P##1 = make_float2(e1_.x+o1_.x, e1_.y+o1_.y); \
    P##5 = make_float2(e1_.x-o1_.x, e1_.y-o1_.y); \
    P##2 = make_float2(e2_.x+o2_.x, e2_.y+o2_.y); \
    P##6 = make_float2(e2_.x-o2_.x, e2_.y-o2_.y); \
    P##3 = make_float2(e3_.x+o3_.x, e3_.y+o3_.y); \
    P##7 = make_float2(e3_.x-o3_.x, e3_.y-o3_.y); }

#define TWCHAIN(P, W) { float2 f_ = W; \
    P##1 = cmul(P##1, f_); f_ = cmul(f_, W); \
    P##2 = cmul(P##2, f_); f_ = cmul(f_, W); \
    P##3 = cmul(P##3, f_); f_ = cmul(f_, W); \
    P##4 = cmul(P##4, f_); f_ = cmul(f_, W); \
    P##5 = cmul(P##5, f_); f_ = cmul(f_, W); \
    P##6 = cmul(P##6, f_); f_ = cmul(f_, W); \
    P##7 = cmul(P##7, f_); }

// ---------------- K1: row DCT (unchanged) ----------------

template <int Q>
__device__ __forceinline__ void stage_pair(float2* lds, int t) {
    const int j = t & (Q - 1);
    const int G = t / Q;
    const int base = G * 16 * Q + j;

    float2 v[4][4];
#pragma unroll
    for (int b = 0; b < 4; ++b)
#pragma unroll
        for (int a = 0; a < 4; ++a)
            v[a][b] = lds[SWZ(base + (a + 4 * b) * Q)];

    if (Q > 1) {
        float c1, s1;
        __sincosf((float)j * (-6.2831853071795864769f / (4.0f * (float)Q)), &s1, &c1);
        float2 w1 = make_float2(c1, s1);
        float2 w2 = cmul(w1, w1);
        float2 w3 = cmul(w2, w1);
#pragma unroll
        for (int b = 0; b < 4; ++b) {
            v[1][b] = cmul(v[1][b], w1);
            v[2][b] = cmul(v[2][b], w2);
            v[3][b] = cmul(v[3][b], w3);
        }
    }
#pragma unroll
    for (int b = 0; b < 4; ++b) bfly4(v[0][b], v[1][b], v[2][b], v[3][b]);

    float2 u;
    if (Q == 1) {
        u = make_float2(1.0f, 0.0f);
    } else {
        float cu, su;
        __sincosf((float)j * (-6.2831853071795864769f / (16.0f * (float)Q)), &su, &cu);
        u = make_float2(cu, su);
    }
    const float2 E = make_float2(0.92387953251128674f, -0.38268343236508977f);
    float2 w = u;
#pragma unroll
    for (int a = 0; a < 4; ++a) {
        if (!(Q == 1 && a == 0)) {
            float2 W2 = cmul(w, w);
            float2 W3 = cmul(W2, w);
            v[a][1] = cmul(v[a][1], w);
            v[a][2] = cmul(v[a][2], W2);
            v[a][3] = cmul(v[a][3], W3);
        }
        bfly4(v[a][0], v[a][1], v[a][2], v[a][3]);
        if (a < 3) w = cmul(w, E);
    }

#pragma unroll
    for (int b = 0; b < 4; ++b)
#pragma unroll
        for (int a = 0; a < 4; ++a)
            lds[SWZ(base + (a + 4 * b) * Q)] = v[a][b];
}

__global__ __launch_bounds__(256)
void dct_rows2_kernel(const float* __restrict__ in, float* __restrict__ out) {
    __shared__ float2 lds[L];   // 32 KB

    const int r0 = blockIdx.x * 2;
    const int t = threadIdx.x;
    const float* rowA = in + (size_t)r0 * L;
    const float* rowB = rowA + L;

    const int revT4 = ((t & 3) << 6) | ((t & 12) << 2) | ((t >> 2) & 12) | ((t >> 6) & 3);

#pragma unroll
    for (int w = 0; w < 8; ++w) {
        int n = w * 256 + t;
        float2 fa = *reinterpret_cast<const float2*>(&rowA[2 * n]);
        float2 fb = *reinterpret_cast<const float2*>(&rowB[2 * n]);
        int p = (revT4 << 4) | ((w & 3) << 2) | (w >> 2);
        lds[SWZ(p)]        = make_float2(fa.x, fb.x);
        lds[SWZ(4095 - p)] = make_float2(fa.y, fb.y);
    }
    __syncthreads();

    stage_pair<1>(lds, t);
    __syncthreads();
    stage_pair<16>(lds, t);
    __syncthreads();
    stage_pair<256>(lds, t);
    __syncthreads();

    float* outA = out + (size_t)r0 * L;
    float* outB = outA + L;

    float2 e;
    __sincosf((float)t * 3.8349519697141029e-4f, &e.y, &e.x);   // pi*t/8192
    const float2 ST = make_float2(0.99518472667219693f, 0.09801714032956060f); // e^{i pi/32}
#pragma unroll
    for (int w = 0; w < 16; ++w) {
        int k = w * 256 + t;
        float2 Zk = lds[SWZ(k)];
        int m = (L - k) & (L - 1);
        float2 Zm = lds[SWZ(m)];

        float vax = 0.5f * (Zk.x + Zm.x);
        float vay = 0.5f * (Zk.y - Zm.y);
        float vbx = 0.5f * (Zk.y + Zm.y);
        float vby = 0.5f * (Zm.x - Zk.x);

        outA[k] = vax * e.x + vay * e.y;
        outB[k] = vbx * e.x + vby * e.y;
        e = cmul(e, ST);
    }
}

// ---------------- K2a: cooperative column pass, step 1 (unchanged) ----------------
__global__ __launch_bounds__(512)
void fft64_col_a2(const float* __restrict__ Y, float* __restrict__ ws) {
    __shared__ float2 xch[4096];            // [v][t][c], 32 KB
    const int c = threadIdx.x & 63;
    const int v = threadIdx.x >> 6;         // 0..7
    const int b = blockIdx.x;               // 0..63
    const int T = blockIdx.y;               // 0..31
    const int ca = T * 128 + c;
    const int cb = ca + 64;

#define LDA(u) float2 g##u; { \
        const int aa = 8 * u + v; \
        const int row = (u < 4) ? (128 * aa + 2 * b) : (8191 - 128 * aa - 2 * b); \
        const float* rp = Y + (size_t)row * L; \
        g##u = make_float2(rp[ca], rp[cb]); }
    FOR8(LDA)
#undef LDA

    FFT8N(g)                                // over u -> G[t][v] in g_t

#define WRA(t) xch[v * 512 + t * 64 + c] = g##t;
    FOR8(WRA)
#undef WRA
    __syncthreads();
#define RDA(vv) g##vv = xch[vv * 512 + v * 64 + c];
    FOR8(RDA)
#undef RDA

    float2 wv; __sincosf((float)v * -0.09817477042468103f, &wv.y, &wv.x); // -2pi v/64
    TWCHAIN(g, wv)

    FFT8N(g)                                // -> Z[q], q = 8s+v, in g_s

    float2 mw, ms;
    __sincosf((float)(b * v) * -1.5339807878856412e-3f, &mw.y, &mw.x);
    __sincosf((float)b * -1.2271846303085130e-2f, &ms.y, &ms.x);   // -pi b/256
    float2* wp = reinterpret_cast<float2*>(ws) + (size_t)b * 2048 + (size_t)T * 64 + c;
#define STA(s) { \
        g##s = cmul(g##s, mw); \
        wp[(size_t)(8 * s + v) * 131072] = g##s; \
        mw = cmul(mw, ms); }
    FOR8(STA)
#undef STA
}

// ---------------- K2b: column pass step 2, linearity form ----------------
// Two cooperative FFT64s (Gq, Gq2) + reflected-conjugate combines.
__global__ __launch_bounds__(512)
void fft64_col_b3(const float* __restrict__ wsf, float* __restrict__ out) {
    __shared__ float2 xch[8192];            // [0,4096)=X pane, [4096,8192)=G pane
    const int c  = threadIdx.x & 63;
    const int v  = threadIdx.x >> 6;        // 0..7
    const int qa = blockIdx.x;              // 0..31
    const int T  = blockIdx.y;              // 0..31
    const int q  = qa;
    const int q2 = (qa == 0) ? 32 : 64 - qa;

    const float2* wsc = reinterpret_cast<const float2*>(wsf);
    const size_t cbase = (size_t)T * 64 + c;

#define LDH(u) \
    float2 ha##u = wsc[(size_t)q  * 131072 + (size_t)(8*u+v) * 2048 + cbase]; \
    float2 hp##u = wsc[(size_t)q2 * 131072 + (size_t)(8*u+v) * 2048 + cbase];
    FOR8(LDH)
#undef LDH

    float2 wv; __sincosf((float)v * -0.09817477042468103f, &wv.y, &wv.x);

    // ---- FFT64 #1: Gq = FFT64_b(H[q]) ----
    FFT8N(ha)
#define W1(k) xch[v * 512 + k * 64 + c] = ha##k;
    FOR8(W1)
#undef W1
    __syncthreads();                        // bar1
#define DECLG(i) float2 g##i;
    FOR8(DECLG)
#undef DECLG
#define R1(vv) g##vv = xch[vv * 512 + v * 64 + c];
    FOR8(R1)
#undef R1
    TWCHAIN(g, wv)
    FFT8N(g)                                // -> Gq[8a+v] in g_a

    // keep Gq in regs AND store straight [p][c] into G pane
#define SV(a) float2 gq##a = g##a; xch[4096 + (8*a + v) * 64 + c] = g##a;
    FOR8(SV)
#undef SV
    __syncthreads();                        // bar2: X reads done, G writes posted

    // ---- FFT64 #2: Gq2 = FFT64_b(H[q2]) ----
    FFT8N(hp)
#define W2(k) xch[v * 512 + k * 64 + c] = hp##k;
    FOR8(W2)
#undef W2
    __syncthreads();                        // bar3
#define R2(vv) g##vv = xch[vv * 512 + v * 64 + c];
    FOR8(R2)
#undef R2
    TWCHAIN(g, wv)
    FFT8N(g)                                // -> Gq2[8a+v] in g_a
    __syncthreads();                        // bar4: all X reads done
#define W3(a) xch[(8*a + v) * 64 + c] = g##a;   // Gq2 straight [p][c] into X pane
    FOR8(W3)
#undef W3
    __syncthreads();                        // bar5

    // ---- combine + expk + store ----
    // rows q : F_A = 0.5(Gq[p] + conj(P)),  F_B = -0.5i(Gq[p] - conj(P)),
    //          P = (qa==0) ? Gq[(64-p)&63] : Gq2[63-p]
    // rows q2: P2 = (qa==0) ? Gq2[63-p] : Gq[63-p]
    const float2 STEP = make_float2(0.98078528040323045f, 0.19509032201612827f); // e^{+i pi/16}
    float2 eq, eq2;
    __sincosf((float)(64 * v + q ) * 3.8349519697141029e-4f, &eq.y,  &eq.x);
    __sincosf((float)(64 * v + q2) * 3.8349519697141029e-4f, &eq2.y, &eq2.x);
    const int colA = T * 128 + c;

#define CMB(a) { \
    const int p_ = 8 * a + v; \
    float2 rq  = (qa == 0) ? xch[4096 + (((64 - p_) & 63) * 64) + c] \
                           : xch[(63 - p_) * 64 + c]; \
    float2 rq2 = (qa == 0) ? xch[(63 - p_) * 64 + c] \
                           : xch[4096 + (63 - p_) * 64 + c]; \
    float FAx = 0.5f * (gq##a.x + rq.x), FAy = 0.5f * (gq##a.y - rq.y); \
    float FBx = 0.5f * (gq##a.y + rq.y), FBy = 0.5f * (rq.x - gq##a.x); \
    size_t rowq = (size_t)(512 * a + 64 * v + q) * L; \
    out[rowq + colA]      = FAx * eq.x + FAy * eq.y; \
    out[rowq + colA + 64] = FBx * eq.x + FBy * eq.y; \
    float GAx = 0.5f * (g##a.x + rq2.x), GAy = 0.5f * (g##a.y - rq2.y); \
    float GBx = 0.5f * (g##a.y + rq2.y), GBy = 0.5f * (rq2.x - g##a.x); \
    size_t rowq2 = (size_t)(512 * a + 64 * v + q2) * L; \
    out[rowq2 + colA]      = GAx * eq2.x + GAy * eq2.y; \
    out[rowq2 + colA + 64] = GBx * eq2.x + GBy * eq2.y; \
    eq = cmul(eq, STEP); eq2 = cmul(eq2, STEP); }
    FOR8(CMB)
#undef CMB
}

extern "C" void kernel_launch(void* const* d_in, const int* in_sizes, int n_in,
                              void* d_out, int out_size, void* d_ws, size_t ws_size,
                              hipStream_t stream) {
    const float* x = (const float*)d_in[0];
    float* out = (float*)d_out;
    float* ws  = (float*)d_ws;   // needs 64 MB

    dct_rows2_kernel<<<L / 2, 256, 0, stream>>>(x, out);        // rows: x -> Y(out)
    fft64_col_a2<<<dim3(64, 32), 512, 0, stream>>>(out, ws);    // Y -> H(ws)
    fft64_col_b3<<<dim3(32, 32), 512, 0, stream>>>(ws, out);    // H -> final(out)
}

// Round 16
// 72.411 us; speedup vs baseline: 2.1243x; 1.1041x over previous
//
#include <hip/hip_runtime.h>
#include <hip/hip_bf16.h>

// 2D DCT-II (4096x4096 fp32).  Round 16:
//   K1  = REWRITTEN dct_rows4: cooperative four-step FFT4096 =
//         FFT64(a) o W4096^{bq} o FFT64(b), each FFT64 as the K2-verified
//         FFT8 -> LDS exchange -> FFT8 pipeline.  512 thr, 2 packed rows,
//         8 float2/thread, literal LDS offsets, pad-65 panes, 9 barriers.
//         (R15 K1 at 42.7us moved the same bytes as K2a's 15us - structure-
//         bound, not BW-bound; this adopts the faster structure.)
//   K2a = cooperative column step 1 (unchanged)
//   K2b = linearity-form column step 2 (unchanged)
// Plan: K1(x->out) ; K2a(out->ws) ; K2b(ws->out).  d_ws needs 64 MB.

#define L 4096

__device__ __forceinline__ float2 cmul(float2 a, float2 b) {
    return make_float2(a.x * b.x - a.y * b.y, a.x * b.y + a.y * b.x);
}

__device__ __forceinline__ void bfly4(float2& x0, float2& x1, float2& x2, float2& x3) {
    float t0x = x0.x + x2.x, t0y = x0.y + x2.y;
    float t1x = x0.x - x2.x, t1y = x0.y - x2.y;
    float t2x = x1.x + x3.x, t2y = x1.y + x3.y;
    float t3x = x1.x - x3.x, t3y = x1.y - x3.y;
    x0 = make_float2(t0x + t2x, t0y + t2y);
    x1 = make_float2(t1x + t3y, t1y - t3x);   // t1 + (-i)*t3
    x2 = make_float2(t0x - t2x, t0y - t2y);
    x3 = make_float2(t1x - t3y, t1y + t3x);   // t1 + (+i)*t3
}

#define FOR4(X) X(0) X(1) X(2) X(3)
#define FOR8(X) X(0) X(1) X(2) X(3) X(4) X(5) X(6) X(7)

// 8-point DFT on named regs P0..P7, natural in -> natural out (DIT):
#define FFT8N(P) \
  bfly4(P##0, P##2, P##4, P##6); \
  bfly4(P##1, P##3, P##5, P##7); \
  { float2 e1_=P##2, e2_=P##4, e3_=P##6, o0_=P##1, o1_=P##3, o2_=P##5, o3_=P##7; \
    o1_ = cmul(o1_, make_float2(0.70710678118654752f, -0.70710678118654752f)); \
    o2_ = make_float2(o2_.y, -o2_.x); \
    o3_ = cmul(o3_, make_float2(-0.70710678118654752f, -0.70710678118654752f)); \
    float2 e0_=P##0; \
    P##0 = make_float2(e0_.x+o0_.x, e0_.y+o0_.y); \
    P##4 = make_float2(e0_.x-o0_.x, e0_.y-o0_.y); \
    P##1 = make_float2(e1_.x+o1_.x, e1_.y+o1_.y); \
    P##5 = make_float2(e1_.x-o1_.x, e1_.y-o1_.y); \
    P##2 = make_float2(e2_.x+o2_.x, e2_.y+o2_.y); \
    P##6 = make_float2(e2_.x-o2_.x, e2_.y-o2_.y); \
    P##3 = make_float2(e3_.x+o3_.x, e3_.y+o3_.y); \
    P##7 = make_float2(e3_.x-o3_.x, e3_.y-o3_.y); }

#define TWCHAIN(P, W) { float2 f_ = W; \
    P##1 = cmul(P##1, f_); f_ = cmul(f_, W); \
    P##2 = cmul(P##2, f_); f_ = cmul(f_, W); \
    P##3 = cmul(P##3, f_); f_ = cmul(f_, W); \
    P##4 = cmul(P##4, f_); f_ = cmul(f_, W); \
    P##5 = cmul(P##5, f_); f_ = cmul(f_, W); \
    P##6 = cmul(P##6, f_); f_ = cmul(f_, W); \
    P##7 = cmul(P##7, f_); }

// ---------------- K1: cooperative row DCT ----------------
// Thread (l = lane 0..63, v = wave 0..7).  n = 64a + b; step 1 lanes = b,
// step 2 lanes = q.  Panes: natural [n], [v][t][l], padded [q][b] (65),
// [v][t][l], padded [p][q] (65).
__global__ __launch_bounds__(512)
void dct_rows4_kernel(const float* __restrict__ in, float* __restrict__ out) {
    __shared__ float2 xch[4160];            // 33,280 B
    const int l = threadIdx.x & 63;
    const int v = threadIdx.x >> 6;
    const int r0 = blockIdx.x * 2;
    const float* rowA = in + (size_t)r0 * L;
    const float* rowB = rowA + L;

    // trip 1: Makhoul distribute.  n = 512u + 64v + l (u<4) covers [0,2048);
    // float2 at x[2n] = (v[n], v[4095-n]).
#define LD1(u) { \
        const int n = 512*u + 64*v + l; \
        float2 fa = *reinterpret_cast<const float2*>(&rowA[2*n]); \
        float2 fb = *reinterpret_cast<const float2*>(&rowB[2*n]); \
        xch[n]        = make_float2(fa.x, fb.x); \
        xch[4095 - n] = make_float2(fa.y, fb.y); }
    FOR4(LD1)
#undef LD1
    __syncthreads();                        // B1
#define R1(u) float2 g##u = xch[512*u + 64*v + l];
    FOR8(R1)
#undef R1
    __syncthreads();                        // B2 (WAR)

    // ---- FFT64 over a (a = 8u+v), fixed b = l ----
    FFT8N(g)
#define W2(t) xch[512*v + 64*t + l] = g##t;
    FOR8(W2)
#undef W2
    __syncthreads();                        // B3
#define R2(vv) g##vv = xch[512*vv + 64*v + l];
    FOR8(R2)
#undef R2
    __syncthreads();                        // B4 (WAR)

    float2 wv; __sincosf((float)v * -0.09817477042468103f, &wv.y, &wv.x); // -2pi v/64
    TWCHAIN(g, wv)
    FFT8N(g)                                // -> H[q = 8s+v][b = l] in g_s

    // mid twiddle W4096^{l*q}: anchor e^{-2pi l v/4096}, step e^{-pi l/256}
    float2 mw, ms;
    __sincosf((float)(l * v) * -1.5339807878856412e-3f, &mw.y, &mw.x);
    __sincosf((float)l * -1.2271846303085130e-2f, &ms.y, &ms.x);
#define W3(s) { g##s = cmul(g##s, mw); xch[520*s + 65*v + l] = g##s; mw = cmul(mw, ms); }
    FOR8(W3)
#undef W3
    __syncthreads();                        // B5
    // redistribute: role q' = l; f_u = H[l][8u+v] at [65*l + 8u + v]
#define R3(u) g##u = xch[65*l + 8*u + v];
    FOR8(R3)
#undef R3
    __syncthreads();                        // B6 (WAR)

    // ---- FFT64 over b (b = 8u+v), fixed q = l ----
    FFT8N(g)
#define W4(t) xch[512*v + 64*t + l] = g##t;
    FOR8(W4)
#undef W4
    __syncthreads();                        // B7
#define R4(vv) g##vv = xch[512*vv + 64*v + l];
    FOR8(R4)
#undef R4
    __syncthreads();                        // B8 (WAR)

    TWCHAIN(g, wv)
    FFT8N(g)                                // -> X[512s + 64v + l] in g_s

    // trip 5: pane [p][q] (pad 65), p = 8s+v, q = l
#define W5(s) xch[520*s + 65*v + l] = g##s;
    FOR8(W5)
#undef W5
    __syncthreads();                        // B9

    // epilogue: conj-split + expk.  k = 512s + 64v + l, partner m = (4096-k)&4095
    float* outA = out + (size_t)r0 * L;
    float* outB = outA + L;
    float2 e; __sincosf((float)(64*v + l) * 3.8349519697141029e-4f, &e.y, &e.x); // pi k0/8192
    const float2 ST = make_float2(0.98078528040323045f, 0.19509032201612827f);   // e^{i pi/16}
#define EP5(s) { \
        const int k = 512*s + 64*v + l; \
        const int m = (4096 - k) & 4095; \
        float2 Zk = g##s; \
        float2 Zm = xch[(m >> 6) * 65 + (m & 63)]; \
        float vax = 0.5f*(Zk.x + Zm.x), vay = 0.5f*(Zk.y - Zm.y); \
        float vbx = 0.5f*(Zk.y + Zm.y), vby = 0.5f*(Zm.x - Zk.x); \
        outA[k] = vax*e.x + vay*e.y; \
        outB[k] = vbx*e.x + vby*e.y; \
        e = cmul(e, ST); }
    FOR8(EP5)
#undef EP5
}

// e^{-2*pi*i*M/64} as compile-time literals (used by K2b combine path only
// indirectly; kept for K2a/K2b parity) -- not needed here anymore.

// ---------------- K2a: cooperative column pass, step 1 (unchanged) ----------------
__global__ __launch_bounds__(512)
void fft64_col_a2(const float* __restrict__ Y, float* __restrict__ ws) {
    __shared__ float2 xch[4096];            // [v][t][c], 32 KB
    const int c = threadIdx.x & 63;
    const int v = threadIdx.x >> 6;         // 0..7
    const int b = blockIdx.x;               // 0..63
    const int T = blockIdx.y;               // 0..31
    const int ca = T * 128 + c;
    const int cb = ca + 64;

#define LDA(u) float2 g##u; { \
        const int aa = 8 * u + v; \
        const int row = (u < 4) ? (128 * aa + 2 * b) : (8191 - 128 * aa - 2 * b); \
        const float* rp = Y + (size_t)row * L; \
        g##u = make_float2(rp[ca], rp[cb]); }
    FOR8(LDA)
#undef LDA

    FFT8N(g)                                // over u -> G[t][v] in g_t

#define WRA(t) xch[v * 512 + t * 64 + c] = g##t;
    FOR8(WRA)
#undef WRA
    __syncthreads();
#define RDA(vv) g##vv = xch[vv * 512 + v * 64 + c];
    FOR8(RDA)
#undef RDA

    float2 wv; __sincosf((float)v * -0.09817477042468103f, &wv.y, &wv.x); // -2pi v/64
    TWCHAIN(g, wv)

    FFT8N(g)                                // -> Z[q], q = 8s+v, in g_s

    float2 mw, ms;
    __sincosf((float)(b * v) * -1.5339807878856412e-3f, &mw.y, &mw.x);
    __sincosf((float)b * -1.2271846303085130e-2f, &ms.y, &ms.x);   // -pi b/256
    float2* wp = reinterpret_cast<float2*>(ws) + (size_t)b * 2048 + (size_t)T * 64 + c;
#define STA(s) { \
        g##s = cmul(g##s, mw); \
        wp[(size_t)(8 * s + v) * 131072] = g##s; \
        mw = cmul(mw, ms); }
    FOR8(STA)
#undef STA
}

// ---------------- K2b: column pass step 2, linearity form (unchanged) ----------------
__global__ __launch_bounds__(512)
void fft64_col_b3(const float* __restrict__ wsf, float* __restrict__ out) {
    __shared__ float2 xch[8192];            // [0,4096)=X pane, [4096,8192)=G pane
    const int c  = threadIdx.x & 63;
    const int v  = threadIdx.x >> 6;        // 0..7
    const int qa = blockIdx.x;              // 0..31
    const int T  = blockIdx.y;               // 0..31
    const int q  = qa;
    const int q2 = (qa == 0) ? 32 : 64 - qa;

    const float2* wsc = reinterpret_cast<const float2*>(wsf);
    const size_t cbase = (size_t)T * 64 + c;

#define LDH(u) \
    float2 ha##u = wsc[(size_t)q  * 131072 + (size_t)(8*u+v) * 2048 + cbase]; \
    float2 hp##u = wsc[(size_t)q2 * 131072 + (size_t)(8*u+v) * 2048 + cbase];
    FOR8(LDH)
#undef LDH

    float2 wv; __sincosf((float)v * -0.09817477042468103f, &wv.y, &wv.x);

    // ---- FFT64 #1: Gq = FFT64_b(H[q]) ----
    FFT8N(ha)
#define W1(k) xch[v * 512 + k * 64 + c] = ha##k;
    FOR8(W1)
#undef W1
    __syncthreads();                        // bar1
#define DECLG(i) float2 g##i;
    FOR8(DECLG)
#undef DECLG
#define R1b(vv) g##vv = xch[vv * 512 + v * 64 + c];
    FOR8(R1b)
#undef R1b
    TWCHAIN(g, wv)
    FFT8N(g)                                // -> Gq[8a+v] in g_a

#define SV(a) float2 gq##a = g##a; xch[4096 + (8*a + v) * 64 + c] = g##a;
    FOR8(SV)
#undef SV
    __syncthreads();                        // bar2

    // ---- FFT64 #2: Gq2 = FFT64_b(H[q2]) ----
    FFT8N(hp)
#define W2b(k) xch[v * 512 + k * 64 + c] = hp##k;
    FOR8(W2b)
#undef W2b
    __syncthreads();                        // bar3
#define R2b(vv) g##vv = xch[vv * 512 + v * 64 + c];
    FOR8(R2b)
#undef R2b
    TWCHAIN(g, wv)
    FFT8N(g)                                // -> Gq2[8a+v] in g_a
    __syncthreads();                        // bar4
#define W3b(a) xch[(8*a + v) * 64 + c] = g##a;
    FOR8(W3b)
#undef W3b
    __syncthreads();                        // bar5

    const float2 STEP = make_float2(0.98078528040323045f, 0.19509032201612827f); // e^{+i pi/16}
    float2 eq, eq2;
    __sincosf((float)(64 * v + q ) * 3.8349519697141029e-4f, &eq.y,  &eq.x);
    __sincosf((float)(64 * v + q2) * 3.8349519697141029e-4f, &eq2.y, &eq2.x);
    const int colA = T * 128 + c;

#define CMB(a) { \
    const int p_ = 8 * a + v; \
    float2 rq  = (qa == 0) ? xch[4096 + (((64 - p_) & 63) * 64) + c] \
                           : xch[(63 - p_) * 64 + c]; \
    float2 rq2 = (qa == 0) ? xch[(63 - p_) * 64 + c] \
                           : xch[4096 + (63 - p_) * 64 + c]; \
    float FAx = 0.5f * (gq##a.x + rq.x), FAy = 0.5f * (gq##a.y - rq.y); \
    float FBx = 0.5f * (gq##a.y + rq.y), FBy = 0.5f * (rq.x - gq##a.x); \
    size_t rowq = (size_t)(512 * a + 64 * v + q) * L; \
    out[rowq + colA]      = FAx * eq.x + FAy * eq.y; \
    out[rowq + colA + 64] = FBx * eq.x + FBy * eq.y; \
    float GAx = 0.5f * (g##a.x + rq2.x), GAy = 0.5f * (g##a.y - rq2.y); \
    float GBx = 0.5f * (g##a.y + rq2.y), GBy = 0.5f * (rq2.x - g##a.x); \
    size_t rowq2 = (size_t)(512 * a + 64 * v + q2) * L; \
    out[rowq2 + colA]      = GAx * eq2.x + GAy * eq2.y; \
    out[rowq2 + colA + 64] = GBx * eq2.x + GBy * eq2.y; \
    eq = cmul(eq, STEP); eq2 = cmul(eq2, STEP); }
    FOR8(CMB)
#undef CMB
}

extern "C" void kernel_launch(void* const* d_in, const int* in_sizes, int n_in,
                              void* d_out, int out_size, void* d_ws, size_t ws_size,
                              hipStream_t stream) {
    const float* x = (const float*)d_in[0];
    float* out = (float*)d_out;
    float* ws  = (float*)d_ws;   // needs 64 MB

    dct_rows4_kernel<<<L / 2, 512, 0, stream>>>(x, out);        // rows: x -> Y(out)
    fft64_col_a2<<<dim3(64, 32), 512, 0, stream>>>(out, ws);    // Y -> H(ws)
    fft64_col_b3<<<dim3(32, 32), 512, 0, stream>>>(ws, out);    // H -> final(out)
}